// Round 6
// baseline (354.096 us; speedup 1.0000x reference)
//
#include <hip/hip_runtime.h>

#define D_MODEL 1024
#define D_FFN   4096
#define SEQ     2048
#define NROWS   4096   // B*S
#define QKV_LD  3072

typedef __bf16 bf16x8 __attribute__((ext_vector_type(8)));
typedef float  floatx4 __attribute__((ext_vector_type(4)));

#define MFMA_BF16 __builtin_amdgcn_mfma_f32_16x16x32_bf16

__device__ __forceinline__ unsigned short f2bf(float f) {
  unsigned int u = __float_as_uint(f);
  u += 0x7FFFu + ((u >> 16) & 1u);   // RNE
  return (unsigned short)(u >> 16);
}

// DPP row_ror<N> within 16-lane rows (VALU-speed cross-lane; no LDS pipe)
template <int C>
__device__ __forceinline__ float ror16(float x) {
  return __int_as_float(
      __builtin_amdgcn_mov_dpp(__float_as_int(x), 0x120 | C, 0xf, 0xf, true));
}

// async global->LDS, 16B per lane. LDS dest = wave-uniform base + lane*16.
__device__ __forceinline__ void async16(const unsigned short* g, unsigned short* l) {
  __builtin_amdgcn_global_load_lds(
      (const __attribute__((address_space(1))) unsigned int*)g,
      (__attribute__((address_space(3))) unsigned int*)l, 16, 0, 0);
}

// ---------------- fp32 -> bf16 elementwise ----------------
__global__ __launch_bounds__(256) void k_f32_to_bf16(
    const float* __restrict__ in, unsigned short* __restrict__ outp, long n) {
  long i = ((long)blockIdx.x * 256 + threadIdx.x) * 4;
  if (i >= n) return;
  float4 v = *(const float4*)(in + i);
  ushort4 o;
  o.x = f2bf(v.x); o.y = f2bf(v.y); o.z = f2bf(v.z); o.w = f2bf(v.w);
  *(ushort4*)(outp + i) = o;
}

// ------------- transpose+convert: W[R][C] f32 -> WT[C][R] bf16 -------------
__global__ __launch_bounds__(256) void k_transpose_bf16(
    const float* __restrict__ W, unsigned short* __restrict__ WT, int R, int C) {
  __shared__ float tile[32][33];
  int tx = threadIdx.x & 31, ty = threadIdx.x >> 5;
  long bx = (long)blockIdx.x * 32;
  long by = (long)blockIdx.y * 32;
  #pragma unroll
  for (int j = 0; j < 4; j++)
    tile[ty + j * 8][tx] = W[(by + ty + j * 8) * C + bx + tx];
  __syncthreads();
  #pragma unroll
  for (int j = 0; j < 4; j++)
    WT[(bx + ty + j * 8) * R + by + tx] = f2bf(tile[tx][ty + j * 8]);
}

// ------------- 1024x1024 weight transposes fused (z: Wq,Wk,Wv -> WqkvT; Wo -> WoT) ------
__global__ __launch_bounds__(256) void k_transpose_sq(
    const float* __restrict__ Wq, const float* __restrict__ Wk,
    const float* __restrict__ Wv, const float* __restrict__ Wo,
    unsigned short* __restrict__ WqkvT, unsigned short* __restrict__ WoT) {
  __shared__ float tile[32][33];
  int z = blockIdx.z;
  const float* W = (z == 0) ? Wq : (z == 1) ? Wk : (z == 2) ? Wv : Wo;
  unsigned short* dst = (z < 3) ? (WqkvT + (size_t)z * D_MODEL * D_MODEL) : WoT;
  int tx = threadIdx.x & 31, ty = threadIdx.x >> 5;
  long bx = (long)blockIdx.x * 32;
  long by = (long)blockIdx.y * 32;
  #pragma unroll
  for (int j = 0; j < 4; j++)
    tile[ty + j * 8][tx] = W[(by + ty + j * 8) * D_MODEL + bx + tx];
  __syncthreads();
  #pragma unroll
  for (int j = 0; j < 4; j++)
    dst[(bx + ty + j * 8) * D_MODEL + by + tx] = f2bf(tile[tx][ty + j * 8]);
}

__global__ __launch_bounds__(256) void k_pack_bias(
    const float* __restrict__ bq, const float* __restrict__ bk,
    const float* __restrict__ bv, float* __restrict__ dst) {
  int i = blockIdx.x * 256 + threadIdx.x;
  if (i >= 3072) return;
  float v = (i < 1024) ? bq[i] : (i < 2048) ? bk[i - 1024] : bv[i - 2048];
  dst[i] = v;
}

// ------------- V^T: QKV[:, 2048+d] -> Vt[d][row]  (bf16) -------------
__global__ __launch_bounds__(256) void k_transpose_v(
    const unsigned short* __restrict__ QKV, unsigned short* __restrict__ Vt) {
  __shared__ unsigned short tile[64][72];
  int r0 = blockIdx.x * 64;
  int c0 = blockIdx.y * 64;
  int tx = threadIdx.x & 15, ty = threadIdx.x >> 4;
  #pragma unroll
  for (int j = 0; j < 4; j++) {
    int r = ty + j * 16;
    *(ushort4*)&tile[r][tx * 4] =
        *(const ushort4*)(QKV + (long)(r0 + r) * QKV_LD + 2048 + c0 + tx * 4);
  }
  __syncthreads();
  #pragma unroll
  for (int j = 0; j < 4; j++) {
    int d = ty + j * 16;
    ushort4 o;
    o.x = tile[tx * 4 + 0][d];
    o.y = tile[tx * 4 + 1][d];
    o.z = tile[tx * 4 + 2][d];
    o.w = tile[tx * 4 + 3][d];
    *(ushort4*)(Vt + (long)(c0 + d) * NROWS + r0 + tx * 4) = o;
  }
}

// ============ 128x128 8-wave bf16 MFMA GEMM, counted vmcnt, 2D XCD chunking ============
// C[M][N] = A[M][K] @ Bt[N][K]^T + bias. BK=64.
// NBUF=2: 64 KiB LDS, 1-tile prefetch, vmcnt(4)  -> 2 blocks/CU (TLP overlap).
// NBUF=3: 96 KiB LDS, 2-tile prefetch, vmcnt(8)  -> for 256-block grids that are
//         1 block/CU regardless: ~2 iterations (>1500 cyc) of HBM-latency slack (ILP).
// Hazard audit (NBUF=3): stage at iter t writes buf (t+2)%3 == (t-1)%3; all reads of
// tile t-1 completed before the trailing barrier of iter t-1. Dummy tail stages keep
// the outstanding-load count uniform so vmcnt(8) always covers exactly tiles t+1,t+2.
// XCD chunking: grid (nx x ny) split into rx x ry rects (rx*ry=8); XCD x owns rect
// (x/ry, x%ry) walked im-fast. bf16 out: LDS-staged coalesced epilogue (64B lines).
template <int NBUF>
__global__ __launch_bounds__(512, 4) void k_gemm128(
    const unsigned short* __restrict__ A,
    const unsigned short* __restrict__ Bt,
    const float* __restrict__ bias,
    void* __restrict__ Cp, int M, int N, int K, int flags, int rx, int ry) {
  __shared__ unsigned short lds[NBUF * 16384];
  int tid = threadIdx.x, lane = tid & 63, wave = tid >> 6;
  int quad = lane >> 4, l16 = lane & 15;
  int wm = wave >> 2, wn = wave & 3;          // 2M x 4N wave grid

  int nx = gridDim.x, ny = gridDim.y;
  int orig = blockIdx.y * nx + blockIdx.x;
  int xcd = orig & 7;                 // assumes round-robin dispatch->XCD (perf-only)
  int s = orig >> 3;                  // sequence within this XCD
  int mr = nx / rx, mc = ny / ry;     // tiles per rect
  int rr = xcd / ry, rc = xcd % ry;
  int im = s % mr, in_ = s / mr;      // im-fast: concurrent blocks share B-panels
  long bm = (long)(rr * mr + im) * 128;
  long bn = (long)(rc * mc + in_) * 128;

  int T = K / 64;

  const floatx4 fz = {0.f, 0.f, 0.f, 0.f};
  floatx4 acc[4][2];
  #pragma unroll
  for (int i = 0; i < 4; i++)
    #pragma unroll
    for (int j = 0; j < 2; j++) acc[i][j] = fz;

  int srow = tid >> 3;
  int sc = (tid & 7) ^ (srow & 7);
  const unsigned short* Ag = A + (bm + srow) * (long)K + sc * 8;
  const unsigned short* Bg = Bt + (bn + srow) * (long)K + sc * 8;

  auto stage = [&](int tt, int c) {
    unsigned short* An = lds + c * 16384;
    unsigned short* Bn = An + 8192;
    long ko = (long)tt * 64;
    async16(Ag + ko, An + wave * 512);
    async16(Ag + 64 * (long)K + ko, An + 4096 + wave * 512);
    async16(Bg + ko, Bn + wave * 512);
    async16(Bg + 64 * (long)K + ko, Bn + 4096 + wave * 512);
  };

  int aoff = (wm * 64 + l16) * 64;
  int boff = (wn * 32 + l16) * 64;
  int sw = l16 & 7;
  int ca0 = (quad ^ sw) * 8;          // k-chunks 0..3 (h=0)
  int ca1 = ((4 + quad) ^ sw) * 8;    // k-chunks 4..7 (h=1)

  stage(0, 0);
  if (NBUF == 3) stage(1 < T ? 1 : T - 1, 1);
  int c = 0;                                   // buffer being computed
  int cn = (NBUF == 3) ? 2 : 1;                // buffer to stage into
  for (int t = 0; t < T; t++) {
    const unsigned short* Ac = lds + c * 16384;
    const unsigned short* Bc = Ac + 8192;
    int dist = (NBUF == 3) ? 2 : 1;
    int tn = (t + dist < T) ? t + dist : T - 1;   // clamp keeps vmcnt uniform
    stage(tn, cn);
    if (NBUF == 3) {
      __asm__ volatile("s_waitcnt vmcnt(8)" ::: "memory");
    } else {
      __asm__ volatile("s_waitcnt vmcnt(4)" ::: "memory");
    }
    __builtin_amdgcn_s_barrier();

    bf16x8 af[4][2], bfr[2][2];
    #pragma unroll
    for (int m = 0; m < 4; m++) {
      af[m][0] = *(const bf16x8*)(Ac + aoff + m * 1024 + ca0);
      af[m][1] = *(const bf16x8*)(Ac + aoff + m * 1024 + ca1);
    }
    #pragma unroll
    for (int n = 0; n < 2; n++) {
      bfr[n][0] = *(const bf16x8*)(Bc + boff + n * 1024 + ca0);
      bfr[n][1] = *(const bf16x8*)(Bc + boff + n * 1024 + ca1);
    }
    __asm__ volatile("s_waitcnt lgkmcnt(0)" ::: "memory");
    __builtin_amdgcn_s_setprio(1);
    #pragma unroll
    for (int h = 0; h < 2; h++)
      #pragma unroll
      for (int m = 0; m < 4; m++)
        #pragma unroll
        for (int n = 0; n < 2; n++)
          acc[m][n] = MFMA_BF16(af[m][h], bfr[n][h], acc[m][n], 0, 0, 0);
    __builtin_amdgcn_s_setprio(0);
    __builtin_amdgcn_s_barrier();

    c = (c + 1 == NBUF) ? 0 : c + 1;
    cn = (cn + 1 == NBUF) ? 0 : cn + 1;
  }

  bool f32out = (flags & 1) != 0;
  bool relu   = (flags & 2) != 0;
  if (f32out) {
    float* outf = (float*)Cp;
    #pragma unroll
    for (int n = 0; n < 2; n++) {
      long col = bn + wn * 32 + n * 16 + l16;
      float bvv = bias[col];
      #pragma unroll
      for (int m = 0; m < 4; m++) {
        long row = bm + wm * 64 + m * 16 + quad * 4;
        #pragma unroll
        for (int r = 0; r < 4; r++) {
          float v = acc[m][n][r] + bvv;
          if (relu) v = fmaxf(v, 0.0f);
          outf[(row + r) * (long)N + col] = v;
        }
      }
    }
  } else {
    // drain in-flight dummy stage writes before reusing LDS, then barrier
    __asm__ volatile("s_waitcnt vmcnt(0)" ::: "memory");
    __syncthreads();
    unsigned short* outh = (unsigned short*)Cp;
    // per-wave private 64x32 u16 tile, row stride 40 u16
    unsigned short* lw = lds + wave * 2560;
    #pragma unroll
    for (int n = 0; n < 2; n++) {
      long col = bn + wn * 32 + n * 16 + l16;
      float bvv = bias[col];
      #pragma unroll
      for (int m = 0; m < 4; m++) {
        #pragma unroll
        for (int r = 0; r < 4; r++) {
          float v = acc[m][n][r] + bvv;
          if (relu) v = fmaxf(v, 0.0f);
          lw[(m * 16 + quad * 4 + r) * 40 + n * 16 + l16] = f2bf(v);
        }
      }
    }
    // read back row-major and store full 64B lines (b128 per lane)
    int rrb = lane >> 2;
    int c8 = (lane & 3) * 8;
    long grow = bm + wm * 64;
    long gcol = bn + wn * 32 + c8;
    #pragma unroll
    for (int k = 0; k < 4; k++) {
      int rw = rrb + k * 16;
      bf16x8 vv = *(const bf16x8*)(lw + rw * 40 + c8);
      *(bf16x8*)(outh + (grow + rw) * (long)N + gcol) = vv;
    }
  }
}

// ---------------- flash attention (causal), LDS-staged K/V ----------------
// One q-tile (64 rows) per block; 1024 blocks, heavy-first (qt descending).
#define PLD 72
__global__ __launch_bounds__(256) void k_attn(
    const unsigned short* __restrict__ QKV,
    const unsigned short* __restrict__ Vt,
    unsigned short* __restrict__ Omat) {
  __shared__ unsigned short Ks[64 * 64];   // [kv][d], chunk-swizzled
  __shared__ unsigned short Vs[64 * 64];   // [d][kv], chunk-swizzled
  __shared__ unsigned short Ps[4][16 * PLD];
  int tid = threadIdx.x;
  int lane = tid & 63, wave = tid >> 6;
  int quad = lane >> 4, l16 = lane & 15;
  int z = blockIdx.x;
  int bh = z & 31;
  int qt = 31 - (z >> 5);          // heavy blocks dispatch first
  int b = bh >> 4, h = bh & 15;
  long rowbase = (long)b * SEQ;
  int hd0 = h * 64;
  unsigned short* pw = &Ps[wave][0];
  const float SCL = 0.18033688f;   // 0.125 * log2(e)
  const floatx4 fz = {0.f, 0.f, 0.f, 0.f};

  int r_in = lane >> 3;
  int cpos = lane & 7;

  bf16x8 ones;
  #pragma unroll
  for (int i = 0; i < 8; i++) ones[i] = (__bf16)1.0f;

  int q0w = qt * 64 + wave * 16;
  int qrow = q0w + quad * 4;
  int ntiles = qt + 1;

  bf16x8 qf0, qf1;
  {
    const unsigned short* qp_ =
        QKV + (rowbase + q0w + l16) * (long)QKV_LD + hd0 + quad * 8;
    qf0 = *(const bf16x8*)(qp_);
    qf1 = *(const bf16x8*)(qp_ + 32);
  }

  floatx4 ao[4], aol;
  #pragma unroll
  for (int t = 0; t < 4; t++) ao[t] = fz;
  aol = fz;
  float m_i[4];
  #pragma unroll
  for (int r = 0; r < 4; r++) m_i[r] = -3.0e38f;

  for (int it = 0; it < ntiles; it++) {
    int kv0 = it << 6;
    #pragma unroll
    for (int jj = 0; jj < 2; jj++) {
      int j = wave * 2 + jj;
      int r = j * 8 + r_in;
      int c = cpos ^ (r & 7);
      const unsigned short* gk =
          QKV + (rowbase + kv0 + r) * (long)QKV_LD + 1024 + hd0 + c * 8;
      async16(gk, Ks + j * 512);
      const unsigned short* gv =
          Vt + (long)(hd0 + r) * NROWS + rowbase + kv0 + c * 8;
      async16(gv, Vs + j * 512);
    }
    __syncthreads();

    floatx4 sacc[4];
    #pragma unroll
    for (int t = 0; t < 4; t++) {
      int row = t * 16 + l16;
      int sw = row & 7;
      bf16x8 kf0 = *(const bf16x8*)(Ks + row * 64 + (quad ^ sw) * 8);
      bf16x8 kf1 = *(const bf16x8*)(Ks + row * 64 + ((quad + 4) ^ sw) * 8);
      sacc[t] = __builtin_amdgcn_mfma_f32_16x16x32_bf16(qf0, kf0, fz, 0, 0, 0);
      sacc[t] = __builtin_amdgcn_mfma_f32_16x16x32_bf16(qf1, kf1, sacc[t], 0, 0, 0);
    }

    // causal mask on RAW scores (only the diagonal tile)
    if (it == ntiles - 1) {
      #pragma unroll
      for (int t = 0; t < 4; t++) {
        int kvc = kv0 + t * 16 + l16;
        #pragma unroll
        for (int r = 0; r < 4; r++)
          sacc[t][r] = (kvc > qrow + r) ? -1.0e30f : sacc[t][r];
      }
    }

    // max over raw scores (scale commutes with max: SCL > 0)
    float Mg = sacc[0][0];
    #pragma unroll
    for (int t = 0; t < 4; t++)
      #pragma unroll
      for (int r = 0; r < 4; r++) Mg = fmaxf(Mg, sacc[t][r]);
    Mg = fmaxf(Mg, ror16<1>(Mg));
    Mg = fmaxf(Mg, ror16<2>(Mg));
    Mg = fmaxf(Mg, ror16<4>(Mg));
    Mg = fmaxf(Mg, ror16<8>(Mg));
    float Mg_s = Mg * SCL;

    // defer-max: rescale only if the running max grew by > 8
    float m_min = fminf(fminf(m_i[0], m_i[1]), fminf(m_i[2], m_i[3]));
    if (Mg_s > m_min + 8.0f) {
      #pragma unroll
      for (int r = 0; r < 4; r++) {
        float mn = fmaxf(m_i[r], Mg_s);
        float alpha = __builtin_amdgcn_exp2f(m_i[r] - mn);
        m_i[r] = mn;
        #pragma unroll
        for (int t = 0; t < 4; t++) ao[t][r] *= alpha;
        aol[r] *= alpha;
      }
    }

    #pragma unroll
    for (int t = 0; t < 4; t++)
      #pragma unroll
      for (int r = 0; r < 4; r++) {
        float p = __builtin_amdgcn_exp2f(fmaf(sacc[t][r], SCL, -m_i[r]));
        pw[(quad * 4 + r) * PLD + t * 16 + l16] =
            (unsigned short)(__float_as_uint(p) >> 16);
      }

    __asm__ volatile("s_waitcnt lgkmcnt(0)" ::: "memory");
    bf16x8 pf0 = *(const bf16x8*)(pw + l16 * PLD + quad * 8);
    bf16x8 pf1 = *(const bf16x8*)(pw + l16 * PLD + 32 + quad * 8);

    #pragma unroll
    for (int t = 0; t < 4; t++) {
      int row = t * 16 + l16;
      int sw = row & 7;
      bf16x8 vf0 = *(const bf16x8*)(Vs + row * 64 + (quad ^ sw) * 8);
      bf16x8 vf1 = *(const bf16x8*)(Vs + row * 64 + ((quad + 4) ^ sw) * 8);
      ao[t] = __builtin_amdgcn_mfma_f32_16x16x32_bf16(pf0, vf0, ao[t], 0, 0, 0);
      ao[t] = __builtin_amdgcn_mfma_f32_16x16x32_bf16(pf1, vf1, ao[t], 0, 0, 0);
    }
    aol = __builtin_amdgcn_mfma_f32_16x16x32_bf16(pf0, ones, aol, 0, 0, 0);
    aol = __builtin_amdgcn_mfma_f32_16x16x32_bf16(pf1, ones, aol, 0, 0, 0);

    __syncthreads();
  }

  float inv[4];
  #pragma unroll
  for (int r = 0; r < 4; r++) inv[r] = 1.0f / aol[r];
  #pragma unroll
  for (int t = 0; t < 4; t++)
    #pragma unroll
    for (int r = 0; r < 4; r++)
      Omat[(rowbase + qrow + r) * (long)D_MODEL + hd0 + t * 16 + l16] =
          f2bf(ao[t][r] * inv[r]);
}

// -------- fused residual add (x + partial) + layernorm --------
__global__ __launch_bounds__(256) void k_add_ln(
    const float* __restrict__ A, const float* __restrict__ P,
    const float* __restrict__ g, const float* __restrict__ be,
    float* __restrict__ Y, unsigned short* __restrict__ Ybf) {
  __shared__ float sb[4], ssb[4];
  int tid = threadIdx.x;
  long base = (long)blockIdx.x * D_MODEL + tid * 4;
  float4 a  = *(const float4*)(A + base);
  float4 p0 = *(const float4*)(P + base);
  float v0 = a.x + p0.x;
  float v1 = a.y + p0.y;
  float v2 = a.z + p0.z;
  float v3 = a.w + p0.w;
  float s  = v0 + v1 + v2 + v3;
  float ss = v0 * v0 + v1 * v1 + v2 * v2 + v3 * v3;
  #pragma unroll
  for (int o = 32; o >= 1; o >>= 1) {
    s  += __shfl_xor(s, o, 64);
    ss += __shfl_xor(ss, o, 64);
  }
  int wave = tid >> 6;
  if ((tid & 63) == 0) { sb[wave] = s; ssb[wave] = ss; }
  __syncthreads();
  s  = sb[0] + sb[1] + sb[2] + sb[3];
  ss = ssb[0] + ssb[1] + ssb[2] + ssb[3];
  float mu  = s * (1.0f / 1024.0f);
  float var = ss * (1.0f / 1024.0f) - mu * mu;
  float rstd = rsqrtf(var + 1e-6f);
  float4 gv  = *(const float4*)(g + tid * 4);
  float4 bev = *(const float4*)(be + tid * 4);
  float o0 = (v0 - mu) * rstd * gv.x + bev.x;
  float o1 = (v1 - mu) * rstd * gv.y + bev.y;
  float o2 = (v2 - mu) * rstd * gv.z + bev.z;
  float o3 = (v3 - mu) * rstd * gv.w + bev.w;
  if (Y) *(float4*)(Y + base) = make_float4(o0, o1, o2, o3);
  if (Ybf) {
    ushort4 u;
    u.x = f2bf(o0); u.y = f2bf(o1); u.z = f2bf(o2); u.w = f2bf(o3);
    *(ushort4*)(Ybf + base) = u;
  }
}

extern "C" void kernel_launch(void* const* d_in, const int* in_sizes, int n_in,
                              void* d_out, int out_size, void* d_ws, size_t ws_size,
                              hipStream_t stream) {
  (void)in_sizes; (void)n_in; (void)out_size; (void)ws_size;
  const float* x   = (const float*)d_in[0];
  const float* Wq  = (const float*)d_in[1];
  const float* bq  = (const float*)d_in[2];
  const float* Wk  = (const float*)d_in[3];
  const float* bk  = (const float*)d_in[4];
  const float* Wv  = (const float*)d_in[5];
  const float* bv  = (const float*)d_in[6];
  const float* Wo  = (const float*)d_in[7];
  const float* bo  = (const float*)d_in[8];
  const float* g1  = (const float*)d_in[9];
  const float* b1  = (const float*)d_in[10];
  const float* Wup = (const float*)d_in[11];
  const float* bup = (const float*)d_in[12];
  const float* Wdn = (const float*)d_in[13];
  const float* bdn = (const float*)d_in[14];
  const float* g2  = (const float*)d_in[15];
  const float* b2  = (const float*)d_in[16];
  float* out = (float*)d_out;

  char* ws = (char*)d_ws;
  size_t off = 0;
  auto alloc = [&](size_t bytes) {
    char* p = ws + off;
    off = (off + bytes + 255) & ~(size_t)255;
    return p;
  };
  unsigned short* x_bf   = (unsigned short*)alloc((size_t)NROWS * D_MODEL * 2);
  unsigned short* WqkvT  = (unsigned short*)alloc((size_t)QKV_LD * D_MODEL * 2);
  unsigned short* WoT    = (unsigned short*)alloc((size_t)D_MODEL * D_MODEL * 2);
  unsigned short* WupT   = (unsigned short*)alloc((size_t)D_FFN * D_MODEL * 2);
  unsigned short* WdnT   = (unsigned short*)alloc((size_t)D_MODEL * D_FFN * 2);
  float*          bqkv   = (float*)alloc((size_t)QKV_LD * 4);
  unsigned short* qkv_bf = (unsigned short*)alloc((size_t)NROWS * QKV_LD * 2);
  unsigned short* Vt     = (unsigned short*)alloc((size_t)D_MODEL * NROWS * 2);
  unsigned short* mid_bf = (unsigned short*)alloc((size_t)NROWS * D_MODEL * 2);
  float*          x1f    = (float*)alloc((size_t)NROWS * D_MODEL * 4);
  unsigned short* x1bf   = (unsigned short*)alloc((size_t)NROWS * D_MODEL * 2);
  float*          part   = (float*)alloc((size_t)NROWS * D_MODEL * 4);
  unsigned short* h_bf   = (unsigned short*)alloc((size_t)NROWS * D_FFN * 2);

  k_f32_to_bf16<<<4096, 256, 0, stream>>>(x, x_bf, (long)NROWS * D_MODEL);
  k_transpose_sq<<<dim3(32, 32, 4), 256, 0, stream>>>(Wq, Wk, Wv, Wo, WqkvT, WoT);
  k_transpose_bf16<<<dim3(128, 32), 256, 0, stream>>>(Wup, WupT, D_MODEL, D_FFN);
  k_transpose_bf16<<<dim3(32, 128), 256, 0, stream>>>(Wdn, WdnT, D_FFN, D_MODEL);
  k_pack_bias<<<12, 256, 0, stream>>>(bq, bk, bv, bqkv);

  // QKV: M=4096, N=3072, K=1024 -> 768 blocks, NBUF=2 (2 blocks/CU TLP)
  k_gemm128<2><<<dim3(32, 24), 512, 0, stream>>>(x_bf, WqkvT, bqkv, qkv_bf,
                                                 NROWS, QKV_LD, D_MODEL, 0, 4, 2);
  k_transpose_v<<<dim3(64, 16), 256, 0, stream>>>(qkv_bf, Vt);

  // 1024 blocks: 32 q-tiles x 32 (b,h), heavy-first; whole grid co-resident
  k_attn<<<1024, 256, 0, stream>>>(qkv_bf, Vt, mid_bf);

  // Wo: M=4096, N=1024, K=1024 -> 256 blocks (1/CU), NBUF=3 deep pipeline
  k_gemm128<3><<<dim3(32, 8), 512, 0, stream>>>(mid_bf, WoT, bo, part,
                                                NROWS, D_MODEL, D_MODEL, 1, 4, 2);
  k_add_ln<<<4096, 256, 0, stream>>>(x, part, g1, b1, x1f, x1bf);

  // Up: M=4096, N=4096, K=1024 -> 1024 blocks, NBUF=2 (2 blocks/CU TLP)
  k_gemm128<2><<<dim3(32, 32), 512, 0, stream>>>(x1bf, WupT, bup, h_bf,
                                                 NROWS, D_FFN, D_MODEL, 2, 4, 2);
  // Down: M=4096, N=1024, K=4096 -> 256 blocks (1/CU), NBUF=3 deep pipeline
  k_gemm128<3><<<dim3(32, 8), 512, 0, stream>>>(h_bf, WdnT, bdn, part,
                                                NROWS, D_MODEL, D_FFN, 1, 4, 2);
  k_add_ln<<<4096, 256, 0, stream>>>(x1f, part, g2, b2, out, nullptr);
}

// Round 7
// 347.770 us; speedup vs baseline: 1.0182x; 1.0182x over previous
//
#include <hip/hip_runtime.h>

#define D_MODEL 1024
#define D_FFN   4096
#define SEQ     2048
#define NROWS   4096   // B*S
#define QKV_LD  3072

typedef __bf16 bf16x8 __attribute__((ext_vector_type(8)));
typedef float  floatx4 __attribute__((ext_vector_type(4)));

#define MFMA_BF16 __builtin_amdgcn_mfma_f32_16x16x32_bf16

__device__ __forceinline__ unsigned short f2bf(float f) {
  unsigned int u = __float_as_uint(f);
  u += 0x7FFFu + ((u >> 16) & 1u);   // RNE
  return (unsigned short)(u >> 16);
}

// DPP row_ror<N> within 16-lane rows (VALU-speed cross-lane; no LDS pipe)
template <int C>
__device__ __forceinline__ float ror16(float x) {
  return __int_as_float(
      __builtin_amdgcn_mov_dpp(__float_as_int(x), 0x120 | C, 0xf, 0xf, true));
}

// async global->LDS, 16B per lane. LDS dest = wave-uniform base + lane*16.
__device__ __forceinline__ void async16(const unsigned short* g, unsigned short* l) {
  __builtin_amdgcn_global_load_lds(
      (const __attribute__((address_space(1))) unsigned int*)g,
      (__attribute__((address_space(3))) unsigned int*)l, 16, 0, 0);
}

// ---------------- fp32 -> bf16 elementwise ----------------
__global__ __launch_bounds__(256) void k_f32_to_bf16(
    const float* __restrict__ in, unsigned short* __restrict__ outp, long n) {
  long i = ((long)blockIdx.x * 256 + threadIdx.x) * 4;
  if (i >= n) return;
  float4 v = *(const float4*)(in + i);
  ushort4 o;
  o.x = f2bf(v.x); o.y = f2bf(v.y); o.z = f2bf(v.z); o.w = f2bf(v.w);
  *(ushort4*)(outp + i) = o;
}

// ------------- transpose+convert: W[R][C] f32 -> WT[C][R] bf16 -------------
__global__ __launch_bounds__(256) void k_transpose_bf16(
    const float* __restrict__ W, unsigned short* __restrict__ WT, int R, int C) {
  __shared__ float tile[32][33];
  int tx = threadIdx.x & 31, ty = threadIdx.x >> 5;
  long bx = (long)blockIdx.x * 32;
  long by = (long)blockIdx.y * 32;
  #pragma unroll
  for (int j = 0; j < 4; j++)
    tile[ty + j * 8][tx] = W[(by + ty + j * 8) * C + bx + tx];
  __syncthreads();
  #pragma unroll
  for (int j = 0; j < 4; j++)
    WT[(bx + ty + j * 8) * R + by + tx] = f2bf(tile[tx][ty + j * 8]);
}

// ------------- 1024x1024 weight transposes fused (z: Wq,Wk,Wv -> WqkvT; Wo -> WoT) ------
__global__ __launch_bounds__(256) void k_transpose_sq(
    const float* __restrict__ Wq, const float* __restrict__ Wk,
    const float* __restrict__ Wv, const float* __restrict__ Wo,
    unsigned short* __restrict__ WqkvT, unsigned short* __restrict__ WoT) {
  __shared__ float tile[32][33];
  int z = blockIdx.z;
  const float* W = (z == 0) ? Wq : (z == 1) ? Wk : (z == 2) ? Wv : Wo;
  unsigned short* dst = (z < 3) ? (WqkvT + (size_t)z * D_MODEL * D_MODEL) : WoT;
  int tx = threadIdx.x & 31, ty = threadIdx.x >> 5;
  long bx = (long)blockIdx.x * 32;
  long by = (long)blockIdx.y * 32;
  #pragma unroll
  for (int j = 0; j < 4; j++)
    tile[ty + j * 8][tx] = W[(by + ty + j * 8) * D_MODEL + bx + tx];
  __syncthreads();
  #pragma unroll
  for (int j = 0; j < 4; j++)
    dst[(bx + ty + j * 8) * D_MODEL + by + tx] = f2bf(tile[tx][ty + j * 8]);
}

__global__ __launch_bounds__(256) void k_pack_bias(
    const float* __restrict__ bq, const float* __restrict__ bk,
    const float* __restrict__ bv, float* __restrict__ dst) {
  int i = blockIdx.x * 256 + threadIdx.x;
  if (i >= 3072) return;
  float v = (i < 1024) ? bq[i] : (i < 2048) ? bk[i - 1024] : bv[i - 2048];
  dst[i] = v;
}

// ------------- V^T: QKV[:, 2048+d] -> Vt[d][row]  (bf16) -------------
__global__ __launch_bounds__(256) void k_transpose_v(
    const unsigned short* __restrict__ QKV, unsigned short* __restrict__ Vt) {
  __shared__ unsigned short tile[64][72];
  int r0 = blockIdx.x * 64;
  int c0 = blockIdx.y * 64;
  int tx = threadIdx.x & 15, ty = threadIdx.x >> 4;
  #pragma unroll
  for (int j = 0; j < 4; j++) {
    int r = ty + j * 16;
    *(ushort4*)&tile[r][tx * 4] =
        *(const ushort4*)(QKV + (long)(r0 + r) * QKV_LD + 2048 + c0 + tx * 4);
  }
  __syncthreads();
  #pragma unroll
  for (int j = 0; j < 4; j++) {
    int d = ty + j * 16;
    ushort4 o;
    o.x = tile[tx * 4 + 0][d];
    o.y = tile[tx * 4 + 1][d];
    o.z = tile[tx * 4 + 2][d];
    o.w = tile[tx * 4 + 3][d];
    *(ushort4*)(Vt + (long)(c0 + d) * NROWS + r0 + tx * 4) = o;
  }
}

// ============ 128x128 4-wave bf16 MFMA GEMM, 64x64/wave, counted vmcnt ============
// C[M][N] = A[M][K] @ Bt[N][K]^T + bias. BK=64, double-buffered 64 KiB static LDS.
// 256 threads as 2M x 2N waves; per wave acc[4][4] (64x64 out). Per block-iter:
// 4 waves x 16 ds_read_b128 = 64 KB LDS read for 128 MFMA (was 96 KB with the
// 8-wave 64x32 layout) -- the K-loop is LDS-pipe-bound, so reads/FLOP is the lever.
// Staging: 8 async16/thread/iter -> vmcnt(8) waits exactly on the previous tile.
// XCD chunking: grid (nx x ny) split into rx x ry rects (rx*ry=8); XCD x owns rect
// (x/ry, x%ry) walked im-fast. bf16 out: LDS-staged coalesced epilogue.
__global__ __launch_bounds__(256, 2) void k_gemm128(
    const unsigned short* __restrict__ A,
    const unsigned short* __restrict__ Bt,
    const float* __restrict__ bias,
    void* __restrict__ Cp, int M, int N, int K, int flags, int rx, int ry) {
  __shared__ unsigned short lds[2 * 16384];   // [2 buf][A 8192 | B 8192] u16 = 64 KiB
  int tid = threadIdx.x, lane = tid & 63, wave = tid >> 6;
  int quad = lane >> 4, l16 = lane & 15;
  int wm = wave >> 1, wn = wave & 1;          // 2M x 2N wave grid

  int nx = gridDim.x, ny = gridDim.y;
  int orig = blockIdx.y * nx + blockIdx.x;
  int xcd = orig & 7;                 // assumes round-robin dispatch->XCD (perf-only)
  int s = orig >> 3;                  // sequence within this XCD
  int mr = nx / rx, mc = ny / ry;     // tiles per rect
  int rr = xcd / ry, rc = xcd % ry;
  int im = s % mr, in_ = s / mr;      // im-fast: concurrent blocks share B-panels
  long bm = (long)(rr * mr + im) * 128;
  long bn = (long)(rc * mc + in_) * 128;

  int T = K / 64;

  const floatx4 fz = {0.f, 0.f, 0.f, 0.f};
  floatx4 acc[4][4];
  #pragma unroll
  for (int i = 0; i < 4; i++)
    #pragma unroll
    for (int j = 0; j < 4; j++) acc[i][j] = fz;

  // staging: call j covers rows j*32 + (tid>>3); LDS linear (pos = tid&7),
  // global chunk pre-swizzled = (tid&7) ^ (row&7).
  int srow = tid >> 3;
  int sc = (tid & 7) ^ (srow & 7);
  const unsigned short* Ag = A + (bm + srow) * (long)K + sc * 8;
  const unsigned short* Bg = Bt + (bn + srow) * (long)K + sc * 8;

  auto stage = [&](int tt, int c) {
    unsigned short* An = lds + c * 16384;
    unsigned short* Bn = An + 8192;
    long ko = (long)tt * 64;
    #pragma unroll
    for (int j = 0; j < 4; j++)
      async16(Ag + (long)j * 32 * K + ko, An + j * 2048 + wave * 512);
    #pragma unroll
    for (int j = 0; j < 4; j++)
      async16(Bg + (long)j * 32 * K + ko, Bn + j * 2048 + wave * 512);
  };

  // frag read offsets (u16). row&7 == l16&7 for all frag rows.
  int aoff = (wm * 64 + l16) * 64;
  int boff = (wn * 64 + l16) * 64;
  int sw = l16 & 7;
  int ca0 = (quad ^ sw) * 8;          // k-chunks 0..3 (h=0)
  int ca1 = ((4 + quad) ^ sw) * 8;    // k-chunks 4..7 (h=1)

  stage(0, 0);
  for (int t = 0; t < T; t++) {
    int c = t & 1;
    const unsigned short* Ac = lds + c * 16384;
    const unsigned short* Bc = Ac + 8192;
    int tn = (t + 1 < T) ? t + 1 : T - 1;   // clamp keeps vmcnt count uniform
    stage(tn, c ^ 1);
    __asm__ volatile("s_waitcnt vmcnt(8)" ::: "memory");
    __builtin_amdgcn_s_barrier();

    bf16x8 af[4][2], bfr[4][2];
    #pragma unroll
    for (int m = 0; m < 4; m++) {
      af[m][0] = *(const bf16x8*)(Ac + aoff + m * 1024 + ca0);
      af[m][1] = *(const bf16x8*)(Ac + aoff + m * 1024 + ca1);
    }
    #pragma unroll
    for (int n = 0; n < 4; n++) {
      bfr[n][0] = *(const bf16x8*)(Bc + boff + n * 1024 + ca0);
      bfr[n][1] = *(const bf16x8*)(Bc + boff + n * 1024 + ca1);
    }
    __asm__ volatile("s_waitcnt lgkmcnt(0)" ::: "memory");
    __builtin_amdgcn_s_setprio(1);
    #pragma unroll
    for (int h = 0; h < 2; h++)
      #pragma unroll
      for (int m = 0; m < 4; m++)
        #pragma unroll
        for (int n = 0; n < 4; n++)
          acc[m][n] = MFMA_BF16(af[m][h], bfr[n][h], acc[m][n], 0, 0, 0);
    __builtin_amdgcn_s_setprio(0);
    __builtin_amdgcn_s_barrier();
  }

  bool f32out = (flags & 1) != 0;
  bool relu   = (flags & 2) != 0;
  if (f32out) {
    float* outf = (float*)Cp;
    #pragma unroll
    for (int n = 0; n < 4; n++) {
      long col = bn + wn * 64 + n * 16 + l16;
      float bvv = bias[col];
      #pragma unroll
      for (int m = 0; m < 4; m++) {
        long row = bm + wm * 64 + m * 16 + quad * 4;
        #pragma unroll
        for (int r = 0; r < 4; r++) {
          float v = acc[m][n][r] + bvv;
          if (relu) v = fmaxf(v, 0.0f);
          outf[(row + r) * (long)N + col] = v;
        }
      }
    }
  } else {
    // drain in-flight dummy stage writes before reusing LDS, then barrier
    __asm__ volatile("s_waitcnt vmcnt(0)" ::: "memory");
    __syncthreads();
    unsigned short* outh = (unsigned short*)Cp;
    // per-wave private 64x64 u16 tile, row stride 72 u16 (144B, 16B-aligned;
    // quads land on banks +0/8/16/24 -> near-conflict-free writes)
    unsigned short* lw = lds + wave * 4608;
    #pragma unroll
    for (int n = 0; n < 4; n++) {
      long col = bn + wn * 64 + n * 16 + l16;
      float bvv = bias[col];
      #pragma unroll
      for (int m = 0; m < 4; m++) {
        #pragma unroll
        for (int r = 0; r < 4; r++) {
          float v = acc[m][n][r] + bvv;
          if (relu) v = fmaxf(v, 0.0f);
          lw[(m * 16 + quad * 4 + r) * 72 + n * 16 + l16] = f2bf(v);
        }
      }
    }
    // read back row-major; each row = 128B contiguous (8 lanes x b128)
    int rrb = lane >> 3;
    int c8 = (lane & 7) * 8;
    long grow = bm + wm * 64;
    long gcol = bn + wn * 64 + c8;
    #pragma unroll
    for (int k = 0; k < 8; k++) {
      int rw = k * 8 + rrb;
      bf16x8 vv = *(const bf16x8*)(lw + rw * 72 + c8);
      *(bf16x8*)(outh + (grow + rw) * (long)N + gcol) = vv;
    }
  }
}

// ---------------- flash attention (causal), LDS-staged K/V ----------------
// One q-tile (64 rows) per block; 1024 blocks, heavy-first (qt descending).
#define PLD 72
__global__ __launch_bounds__(256) void k_attn(
    const unsigned short* __restrict__ QKV,
    const unsigned short* __restrict__ Vt,
    unsigned short* __restrict__ Omat) {
  __shared__ unsigned short Ks[64 * 64];   // [kv][d], chunk-swizzled
  __shared__ unsigned short Vs[64 * 64];   // [d][kv], chunk-swizzled
  __shared__ unsigned short Ps[4][16 * PLD];
  int tid = threadIdx.x;
  int lane = tid & 63, wave = tid >> 6;
  int quad = lane >> 4, l16 = lane & 15;
  int z = blockIdx.x;
  int bh = z & 31;
  int qt = 31 - (z >> 5);          // heavy blocks dispatch first
  int b = bh >> 4, h = bh & 15;
  long rowbase = (long)b * SEQ;
  int hd0 = h * 64;
  unsigned short* pw = &Ps[wave][0];
  const float SCL = 0.18033688f;   // 0.125 * log2(e)
  const floatx4 fz = {0.f, 0.f, 0.f, 0.f};

  int r_in = lane >> 3;
  int cpos = lane & 7;

  bf16x8 ones;
  #pragma unroll
  for (int i = 0; i < 8; i++) ones[i] = (__bf16)1.0f;

  int q0w = qt * 64 + wave * 16;
  int qrow = q0w + quad * 4;
  int ntiles = qt + 1;

  bf16x8 qf0, qf1;
  {
    const unsigned short* qp_ =
        QKV + (rowbase + q0w + l16) * (long)QKV_LD + hd0 + quad * 8;
    qf0 = *(const bf16x8*)(qp_);
    qf1 = *(const bf16x8*)(qp_ + 32);
  }

  floatx4 ao[4], aol;
  #pragma unroll
  for (int t = 0; t < 4; t++) ao[t] = fz;
  aol = fz;
  float m_i[4];
  #pragma unroll
  for (int r = 0; r < 4; r++) m_i[r] = -3.0e38f;

  for (int it = 0; it < ntiles; it++) {
    int kv0 = it << 6;
    #pragma unroll
    for (int jj = 0; jj < 2; jj++) {
      int j = wave * 2 + jj;
      int r = j * 8 + r_in;
      int c = cpos ^ (r & 7);
      const unsigned short* gk =
          QKV + (rowbase + kv0 + r) * (long)QKV_LD + 1024 + hd0 + c * 8;
      async16(gk, Ks + j * 512);
      const unsigned short* gv =
          Vt + (long)(hd0 + r) * NROWS + rowbase + kv0 + c * 8;
      async16(gv, Vs + j * 512);
    }
    __syncthreads();

    floatx4 sacc[4];
    #pragma unroll
    for (int t = 0; t < 4; t++) {
      int row = t * 16 + l16;
      int sw = row & 7;
      bf16x8 kf0 = *(const bf16x8*)(Ks + row * 64 + (quad ^ sw) * 8);
      bf16x8 kf1 = *(const bf16x8*)(Ks + row * 64 + ((quad + 4) ^ sw) * 8);
      sacc[t] = __builtin_amdgcn_mfma_f32_16x16x32_bf16(qf0, kf0, fz, 0, 0, 0);
      sacc[t] = __builtin_amdgcn_mfma_f32_16x16x32_bf16(qf1, kf1, sacc[t], 0, 0, 0);
    }

    // causal mask on RAW scores (only the diagonal tile)
    if (it == ntiles - 1) {
      #pragma unroll
      for (int t = 0; t < 4; t++) {
        int kvc = kv0 + t * 16 + l16;
        #pragma unroll
        for (int r = 0; r < 4; r++)
          sacc[t][r] = (kvc > qrow + r) ? -1.0e30f : sacc[t][r];
      }
    }

    // max over raw scores (scale commutes with max: SCL > 0)
    float Mg = sacc[0][0];
    #pragma unroll
    for (int t = 0; t < 4; t++)
      #pragma unroll
      for (int r = 0; r < 4; r++) Mg = fmaxf(Mg, sacc[t][r]);
    Mg = fmaxf(Mg, ror16<1>(Mg));
    Mg = fmaxf(Mg, ror16<2>(Mg));
    Mg = fmaxf(Mg, ror16<4>(Mg));
    Mg = fmaxf(Mg, ror16<8>(Mg));
    float Mg_s = Mg * SCL;

    // defer-max: rescale only if the running max grew by > 8
    float m_min = fminf(fminf(m_i[0], m_i[1]), fminf(m_i[2], m_i[3]));
    if (Mg_s > m_min + 8.0f) {
      #pragma unroll
      for (int r = 0; r < 4; r++) {
        float mn = fmaxf(m_i[r], Mg_s);
        float alpha = __builtin_amdgcn_exp2f(m_i[r] - mn);
        m_i[r] = mn;
        #pragma unroll
        for (int t = 0; t < 4; t++) ao[t][r] *= alpha;
        aol[r] *= alpha;
      }
    }

    #pragma unroll
    for (int t = 0; t < 4; t++)
      #pragma unroll
      for (int r = 0; r < 4; r++) {
        float p = __builtin_amdgcn_exp2f(fmaf(sacc[t][r], SCL, -m_i[r]));
        pw[(quad * 4 + r) * PLD + t * 16 + l16] =
            (unsigned short)(__float_as_uint(p) >> 16);
      }

    __asm__ volatile("s_waitcnt lgkmcnt(0)" ::: "memory");
    bf16x8 pf0 = *(const bf16x8*)(pw + l16 * PLD + quad * 8);
    bf16x8 pf1 = *(const bf16x8*)(pw + l16 * PLD + 32 + quad * 8);

    #pragma unroll
    for (int t = 0; t < 4; t++) {
      int row = t * 16 + l16;
      int sw = row & 7;
      bf16x8 vf0 = *(const bf16x8*)(Vs + row * 64 + (quad ^ sw) * 8);
      bf16x8 vf1 = *(const bf16x8*)(Vs + row * 64 + ((quad + 4) ^ sw) * 8);
      ao[t] = __builtin_amdgcn_mfma_f32_16x16x32_bf16(pf0, vf0, ao[t], 0, 0, 0);
      ao[t] = __builtin_amdgcn_mfma_f32_16x16x32_bf16(pf1, vf1, ao[t], 0, 0, 0);
    }
    aol = __builtin_amdgcn_mfma_f32_16x16x32_bf16(pf0, ones, aol, 0, 0, 0);
    aol = __builtin_amdgcn_mfma_f32_16x16x32_bf16(pf1, ones, aol, 0, 0, 0);

    __syncthreads();
  }

  float inv[4];
  #pragma unroll
  for (int r = 0; r < 4; r++) inv[r] = 1.0f / aol[r];
  #pragma unroll
  for (int t = 0; t < 4; t++)
    #pragma unroll
    for (int r = 0; r < 4; r++)
      Omat[(rowbase + qrow + r) * (long)D_MODEL + hd0 + t * 16 + l16] =
          f2bf(ao[t][r] * inv[r]);
}

// -------- fused residual add (x + partial) + layernorm --------
__global__ __launch_bounds__(256) void k_add_ln(
    const float* __restrict__ A, const float* __restrict__ P,
    const float* __restrict__ g, const float* __restrict__ be,
    float* __restrict__ Y, unsigned short* __restrict__ Ybf) {
  __shared__ float sb[4], ssb[4];
  int tid = threadIdx.x;
  long base = (long)blockIdx.x * D_MODEL + tid * 4;
  float4 a  = *(const float4*)(A + base);
  float4 p0 = *(const float4*)(P + base);
  float v0 = a.x + p0.x;
  float v1 = a.y + p0.y;
  float v2 = a.z + p0.z;
  float v3 = a.w + p0.w;
  float s  = v0 + v1 + v2 + v3;
  float ss = v0 * v0 + v1 * v1 + v2 * v2 + v3 * v3;
  #pragma unroll
  for (int o = 32; o >= 1; o >>= 1) {
    s  += __shfl_xor(s, o, 64);
    ss += __shfl_xor(ss, o, 64);
  }
  int wave = tid >> 6;
  if ((tid & 63) == 0) { sb[wave] = s; ssb[wave] = ss; }
  __syncthreads();
  s  = sb[0] + sb[1] + sb[2] + sb[3];
  ss = ssb[0] + ssb[1] + ssb[2] + ssb[3];
  float mu  = s * (1.0f / 1024.0f);
  float var = ss * (1.0f / 1024.0f) - mu * mu;
  float rstd = rsqrtf(var + 1e-6f);
  float4 gv  = *(const float4*)(g + tid * 4);
  float4 bev = *(const float4*)(be + tid * 4);
  float o0 = (v0 - mu) * rstd * gv.x + bev.x;
  float o1 = (v1 - mu) * rstd * gv.y + bev.y;
  float o2 = (v2 - mu) * rstd * gv.z + bev.z;
  float o3 = (v3 - mu) * rstd * gv.w + bev.w;
  if (Y) *(float4*)(Y + base) = make_float4(o0, o1, o2, o3);
  if (Ybf) {
    ushort4 u;
    u.x = f2bf(o0); u.y = f2bf(o1); u.z = f2bf(o2); u.w = f2bf(o3);
    *(ushort4*)(Ybf + base) = u;
  }
}

extern "C" void kernel_launch(void* const* d_in, const int* in_sizes, int n_in,
                              void* d_out, int out_size, void* d_ws, size_t ws_size,
                              hipStream_t stream) {
  (void)in_sizes; (void)n_in; (void)out_size; (void)ws_size;
  const float* x   = (const float*)d_in[0];
  const float* Wq  = (const float*)d_in[1];
  const float* bq  = (const float*)d_in[2];
  const float* Wk  = (const float*)d_in[3];
  const float* bk  = (const float*)d_in[4];
  const float* Wv  = (const float*)d_in[5];
  const float* bv  = (const float*)d_in[6];
  const float* Wo  = (const float*)d_in[7];
  const float* bo  = (const float*)d_in[8];
  const float* g1  = (const float*)d_in[9];
  const float* b1  = (const float*)d_in[10];
  const float* Wup = (const float*)d_in[11];
  const float* bup = (const float*)d_in[12];
  const float* Wdn = (const float*)d_in[13];
  const float* bdn = (const float*)d_in[14];
  const float* g2  = (const float*)d_in[15];
  const float* b2  = (const float*)d_in[16];
  float* out = (float*)d_out;

  char* ws = (char*)d_ws;
  size_t off = 0;
  auto alloc = [&](size_t bytes) {
    char* p = ws + off;
    off = (off + bytes + 255) & ~(size_t)255;
    return p;
  };
  unsigned short* x_bf   = (unsigned short*)alloc((size_t)NROWS * D_MODEL * 2);
  unsigned short* WqkvT  = (unsigned short*)alloc((size_t)QKV_LD * D_MODEL * 2);
  unsigned short* WoT    = (unsigned short*)alloc((size_t)D_MODEL * D_MODEL * 2);
  unsigned short* WupT   = (unsigned short*)alloc((size_t)D_FFN * D_MODEL * 2);
  unsigned short* WdnT   = (unsigned short*)alloc((size_t)D_MODEL * D_FFN * 2);
  float*          bqkv   = (float*)alloc((size_t)QKV_LD * 4);
  unsigned short* qkv_bf = (unsigned short*)alloc((size_t)NROWS * QKV_LD * 2);
  unsigned short* Vt     = (unsigned short*)alloc((size_t)D_MODEL * NROWS * 2);
  unsigned short* mid_bf = (unsigned short*)alloc((size_t)NROWS * D_MODEL * 2);
  float*          x1f    = (float*)alloc((size_t)NROWS * D_MODEL * 4);
  unsigned short* x1bf   = (unsigned short*)alloc((size_t)NROWS * D_MODEL * 2);
  float*          part   = (float*)alloc((size_t)NROWS * D_MODEL * 4);
  unsigned short* h_bf   = (unsigned short*)alloc((size_t)NROWS * D_FFN * 2);

  k_f32_to_bf16<<<4096, 256, 0, stream>>>(x, x_bf, (long)NROWS * D_MODEL);
  k_transpose_sq<<<dim3(32, 32, 4), 256, 0, stream>>>(Wq, Wk, Wv, Wo, WqkvT, WoT);
  k_transpose_bf16<<<dim3(128, 32), 256, 0, stream>>>(Wup, WupT, D_MODEL, D_FFN);
  k_transpose_bf16<<<dim3(32, 128), 256, 0, stream>>>(Wdn, WdnT, D_FFN, D_MODEL);
  k_pack_bias<<<12, 256, 0, stream>>>(bq, bk, bv, bqkv);

  // QKV: M=4096, N=3072, K=1024 -> 768 blocks (2/CU)
  k_gemm128<<<dim3(32, 24), 256, 0, stream>>>(x_bf, WqkvT, bqkv, qkv_bf,
                                              NROWS, QKV_LD, D_MODEL, 0, 4, 2);
  k_transpose_v<<<dim3(64, 16), 256, 0, stream>>>(qkv_bf, Vt);

  // 1024 blocks: 32 q-tiles x 32 (b,h), heavy-first; whole grid co-resident
  k_attn<<<1024, 256, 0, stream>>>(qkv_bf, Vt, mid_bf);

  // Wo: M=4096, N=1024, K=1024 -> 256 blocks, f32 out
  k_gemm128<<<dim3(32, 8), 256, 0, stream>>>(mid_bf, WoT, bo, part,
                                             NROWS, D_MODEL, D_MODEL, 1, 4, 2);
  k_add_ln<<<4096, 256, 0, stream>>>(x, part, g1, b1, x1f, x1bf);

  // Up: M=4096, N=4096, K=1024 -> 1024 blocks (2/CU)
  k_gemm128<<<dim3(32, 32), 256, 0, stream>>>(x1bf, WupT, bup, h_bf,
                                              NROWS, D_FFN, D_MODEL, 2, 4, 2);
  // Down: M=4096, N=1024, K=4096 -> 256 blocks, f32 out
  k_gemm128<<<dim3(32, 8), 256, 0, stream>>>(h_bf, WdnT, bdn, part,
                                             NROWS, D_MODEL, D_FFN, 1, 4, 2);
  k_add_ln<<<4096, 256, 0, stream>>>(x1f, part, g2, b2, out, nullptr);
}

// Round 8
// 334.688 us; speedup vs baseline: 1.0580x; 1.0391x over previous
//
#include <hip/hip_runtime.h>

#define D_MODEL 1024
#define D_FFN   4096
#define SEQ     2048
#define NROWS   4096   // B*S
#define QKV_LD  3072

typedef __bf16 bf16x8 __attribute__((ext_vector_type(8)));
typedef float  floatx4 __attribute__((ext_vector_type(4)));

#define MFMA_BF16 __builtin_amdgcn_mfma_f32_16x16x32_bf16

__device__ __forceinline__ unsigned short f2bf(float f) {
  unsigned int u = __float_as_uint(f);
  u += 0x7FFFu + ((u >> 16) & 1u);   // RNE
  return (unsigned short)(u >> 16);
}

// DPP row_ror<N> within 16-lane rows (VALU-speed cross-lane; no LDS pipe)
template <int C>
__device__ __forceinline__ float ror16(float x) {
  return __int_as_float(
      __builtin_amdgcn_mov_dpp(__float_as_int(x), 0x120 | C, 0xf, 0xf, true));
}

// async global->LDS, 16B per lane. LDS dest = wave-uniform base + lane*16.
__device__ __forceinline__ void async16(const unsigned short* g, unsigned short* l) {
  __builtin_amdgcn_global_load_lds(
      (const __attribute__((address_space(1))) unsigned int*)g,
      (__attribute__((address_space(3))) unsigned int*)l, 16, 0, 0);
}

// ---------------- fp32 -> bf16 elementwise ----------------
__global__ __launch_bounds__(256) void k_f32_to_bf16(
    const float* __restrict__ in, unsigned short* __restrict__ outp, long n) {
  long i = ((long)blockIdx.x * 256 + threadIdx.x) * 4;
  if (i >= n) return;
  float4 v = *(const float4*)(in + i);
  ushort4 o;
  o.x = f2bf(v.x); o.y = f2bf(v.y); o.z = f2bf(v.z); o.w = f2bf(v.w);
  *(ushort4*)(outp + i) = o;
}

// ------------- transpose+convert: W[R][C] f32 -> WT[C][R] bf16 -------------
__global__ __launch_bounds__(256) void k_transpose_bf16(
    const float* __restrict__ W, unsigned short* __restrict__ WT, int R, int C) {
  __shared__ float tile[32][33];
  int tx = threadIdx.x & 31, ty = threadIdx.x >> 5;
  long bx = (long)blockIdx.x * 32;
  long by = (long)blockIdx.y * 32;
  #pragma unroll
  for (int j = 0; j < 4; j++)
    tile[ty + j * 8][tx] = W[(by + ty + j * 8) * C + bx + tx];
  __syncthreads();
  #pragma unroll
  for (int j = 0; j < 4; j++)
    WT[(bx + ty + j * 8) * R + by + tx] = f2bf(tile[tx][ty + j * 8]);
}

// ------------- 1024x1024 weight transposes fused (z: Wq,Wk,Wv -> WqkvT; Wo -> WoT) ------
__global__ __launch_bounds__(256) void k_transpose_sq(
    const float* __restrict__ Wq, const float* __restrict__ Wk,
    const float* __restrict__ Wv, const float* __restrict__ Wo,
    unsigned short* __restrict__ WqkvT, unsigned short* __restrict__ WoT) {
  __shared__ float tile[32][33];
  int z = blockIdx.z;
  const float* W = (z == 0) ? Wq : (z == 1) ? Wk : (z == 2) ? Wv : Wo;
  unsigned short* dst = (z < 3) ? (WqkvT + (size_t)z * D_MODEL * D_MODEL) : WoT;
  int tx = threadIdx.x & 31, ty = threadIdx.x >> 5;
  long bx = (long)blockIdx.x * 32;
  long by = (long)blockIdx.y * 32;
  #pragma unroll
  for (int j = 0; j < 4; j++)
    tile[ty + j * 8][tx] = W[(by + ty + j * 8) * D_MODEL + bx + tx];
  __syncthreads();
  #pragma unroll
  for (int j = 0; j < 4; j++)
    dst[(bx + ty + j * 8) * D_MODEL + by + tx] = f2bf(tile[tx][ty + j * 8]);
}

__global__ __launch_bounds__(256) void k_pack_bias(
    const float* __restrict__ bq, const float* __restrict__ bk,
    const float* __restrict__ bv, float* __restrict__ dst) {
  int i = blockIdx.x * 256 + threadIdx.x;
  if (i >= 3072) return;
  float v = (i < 1024) ? bq[i] : (i < 2048) ? bk[i - 1024] : bv[i - 2048];
  dst[i] = v;
}

// ------------- V^T: QKV[:, 2048+d] -> Vt[d][row]  (bf16) -------------
__global__ __launch_bounds__(256) void k_transpose_v(
    const unsigned short* __restrict__ QKV, unsigned short* __restrict__ Vt) {
  __shared__ unsigned short tile[64][72];
  int r0 = blockIdx.x * 64;
  int c0 = blockIdx.y * 64;
  int tx = threadIdx.x & 15, ty = threadIdx.x >> 4;
  #pragma unroll
  for (int j = 0; j < 4; j++) {
    int r = ty + j * 16;
    *(ushort4*)&tile[r][tx * 4] =
        *(const ushort4*)(QKV + (long)(r0 + r) * QKV_LD + 2048 + c0 + tx * 4);
  }
  __syncthreads();
  #pragma unroll
  for (int j = 0; j < 4; j++) {
    int d = ty + j * 16;
    ushort4 o;
    o.x = tile[tx * 4 + 0][d];
    o.y = tile[tx * 4 + 1][d];
    o.z = tile[tx * 4 + 2][d];
    o.w = tile[tx * 4 + 3][d];
    *(ushort4*)(Vt + (long)(c0 + d) * NROWS + r0 + tx * 4) = o;
  }
}

// ============ 128x128 4-wave bf16 MFMA GEMM, 64x64/wave, counted vmcnt ============
// C[M][N] = A[M][K] @ Bt[N][K]^T + bias. BK=64, double-buffered 64 KiB static LDS.
// 256 threads as 2M x 2N waves; per wave acc[4][4] (64x64 out).
// Schedule: NO intra-phase waitcnt pins -- reads grouped {ca0}{ca1}, MFMAs {h0}{h1},
// so the compiler emits counted lgkmcnt and covers the ca1 ds_reads under the h0
// MFMA block (the m97-style fine interleave; explicit lgkmcnt(0) was serializing
// the LDS pipe against the matrix pipe and pinning MfmaUtil at 25%).
// Staging: 8 async16/thread/iter -> vmcnt(8) waits exactly on the previous tile.
// XCD chunking: grid (nx x ny) split into rx x ry rects (rx*ry=8); XCD x owns rect
// (x/ry, x%ry) walked im-fast. bf16 out: LDS-staged coalesced epilogue.
__global__ __launch_bounds__(256, 2) void k_gemm128(
    const unsigned short* __restrict__ A,
    const unsigned short* __restrict__ Bt,
    const float* __restrict__ bias,
    void* __restrict__ Cp, int M, int N, int K, int flags, int rx, int ry) {
  __shared__ unsigned short lds[2 * 16384];   // [2 buf][A 8192 | B 8192] u16 = 64 KiB
  int tid = threadIdx.x, lane = tid & 63, wave = tid >> 6;
  int quad = lane >> 4, l16 = lane & 15;
  int wm = wave >> 1, wn = wave & 1;          // 2M x 2N wave grid

  int nx = gridDim.x, ny = gridDim.y;
  int orig = blockIdx.y * nx + blockIdx.x;
  int xcd = orig & 7;                 // assumes round-robin dispatch->XCD (perf-only)
  int s = orig >> 3;                  // sequence within this XCD
  int mr = nx / rx, mc = ny / ry;     // tiles per rect
  int rr = xcd / ry, rc = xcd % ry;
  int im = s % mr, in_ = s / mr;      // im-fast: concurrent blocks share B-panels
  long bm = (long)(rr * mr + im) * 128;
  long bn = (long)(rc * mc + in_) * 128;

  int T = K / 64;

  const floatx4 fz = {0.f, 0.f, 0.f, 0.f};
  floatx4 acc[4][4];
  #pragma unroll
  for (int i = 0; i < 4; i++)
    #pragma unroll
    for (int j = 0; j < 4; j++) acc[i][j] = fz;

  // staging: call j covers rows j*32 + (tid>>3); LDS linear (pos = tid&7),
  // global chunk pre-swizzled = (tid&7) ^ (row&7).
  int srow = tid >> 3;
  int sc = (tid & 7) ^ (srow & 7);
  const unsigned short* Ag = A + (bm + srow) * (long)K + sc * 8;
  const unsigned short* Bg = Bt + (bn + srow) * (long)K + sc * 8;

  auto stage = [&](int tt, int c) {
    unsigned short* An = lds + c * 16384;
    unsigned short* Bn = An + 8192;
    long ko = (long)tt * 64;
    #pragma unroll
    for (int j = 0; j < 4; j++)
      async16(Ag + (long)j * 32 * K + ko, An + j * 2048 + wave * 512);
    #pragma unroll
    for (int j = 0; j < 4; j++)
      async16(Bg + (long)j * 32 * K + ko, Bn + j * 2048 + wave * 512);
  };

  // frag read offsets (u16). row&7 == l16&7 for all frag rows.
  int aoff = (wm * 64 + l16) * 64;
  int boff = (wn * 64 + l16) * 64;
  int sw = l16 & 7;
  int ca0 = (quad ^ sw) * 8;          // k-chunks 0..3 (h=0)
  int ca1 = ((4 + quad) ^ sw) * 8;    // k-chunks 4..7 (h=1)

  stage(0, 0);
  for (int t = 0; t < T; t++) {
    int c = t & 1;
    const unsigned short* Ac = lds + c * 16384;
    const unsigned short* Bc = Ac + 8192;
    int tn = (t + 1 < T) ? t + 1 : T - 1;   // clamp keeps vmcnt count uniform
    stage(tn, c ^ 1);
    __asm__ volatile("s_waitcnt vmcnt(8)" ::: "memory");
    __builtin_amdgcn_s_barrier();

    // reads grouped h0-first; MFMAs h0-block then h1-block. No waitcnt pins:
    // the compiler covers the ca1 reads under the h0 MFMAs via counted lgkmcnt.
    bf16x8 af0[4], bf0[4], af1[4], bf1[4];
    #pragma unroll
    for (int m = 0; m < 4; m++) af0[m] = *(const bf16x8*)(Ac + aoff + m * 1024 + ca0);
    #pragma unroll
    for (int n = 0; n < 4; n++) bf0[n] = *(const bf16x8*)(Bc + boff + n * 1024 + ca0);
    #pragma unroll
    for (int m = 0; m < 4; m++) af1[m] = *(const bf16x8*)(Ac + aoff + m * 1024 + ca1);
    #pragma unroll
    for (int n = 0; n < 4; n++) bf1[n] = *(const bf16x8*)(Bc + boff + n * 1024 + ca1);
    #pragma unroll
    for (int m = 0; m < 4; m++)
      #pragma unroll
      for (int n = 0; n < 4; n++)
        acc[m][n] = MFMA_BF16(af0[m], bf0[n], acc[m][n], 0, 0, 0);
    #pragma unroll
    for (int m = 0; m < 4; m++)
      #pragma unroll
      for (int n = 0; n < 4; n++)
        acc[m][n] = MFMA_BF16(af1[m], bf1[n], acc[m][n], 0, 0, 0);
    __builtin_amdgcn_s_barrier();
  }

  bool f32out = (flags & 1) != 0;
  bool relu   = (flags & 2) != 0;
  if (f32out) {
    float* outf = (float*)Cp;
    #pragma unroll
    for (int n = 0; n < 4; n++) {
      long col = bn + wn * 64 + n * 16 + l16;
      float bvv = bias[col];
      #pragma unroll
      for (int m = 0; m < 4; m++) {
        long row = bm + wm * 64 + m * 16 + quad * 4;
        #pragma unroll
        for (int r = 0; r < 4; r++) {
          float v = acc[m][n][r] + bvv;
          if (relu) v = fmaxf(v, 0.0f);
          outf[(row + r) * (long)N + col] = v;
        }
      }
    }
  } else {
    // drain in-flight dummy stage writes before reusing LDS, then barrier
    __asm__ volatile("s_waitcnt vmcnt(0)" ::: "memory");
    __syncthreads();
    unsigned short* outh = (unsigned short*)Cp;
    // per-wave private 64x64 u16 tile, row stride 72 u16 (144B, 16B-aligned;
    // quads land on banks +0/8/16/24 -> near-conflict-free writes)
    unsigned short* lw = lds + wave * 4608;
    #pragma unroll
    for (int n = 0; n < 4; n++) {
      long col = bn + wn * 64 + n * 16 + l16;
      float bvv = bias[col];
      #pragma unroll
      for (int m = 0; m < 4; m++) {
        #pragma unroll
        for (int r = 0; r < 4; r++) {
          float v = acc[m][n][r] + bvv;
          if (relu) v = fmaxf(v, 0.0f);
          lw[(m * 16 + quad * 4 + r) * 72 + n * 16 + l16] = f2bf(v);
        }
      }
    }
    // read back row-major; each row = 128B contiguous (8 lanes x b128)
    int rrb = lane >> 3;
    int c8 = (lane & 7) * 8;
    long grow = bm + wm * 64;
    long gcol = bn + wn * 64 + c8;
    #pragma unroll
    for (int k = 0; k < 8; k++) {
      int rw = k * 8 + rrb;
      bf16x8 vv = *(const bf16x8*)(lw + rw * 72 + c8);
      *(bf16x8*)(outh + (grow + rw) * (long)N + gcol) = vv;
    }
  }
}

// ---------------- flash attention (causal), LDS-staged K/V ----------------
// One q-tile (64 rows) per block; 1024 blocks, heavy-first (qt descending).
#define PLD 72
__global__ __launch_bounds__(256) void k_attn(
    const unsigned short* __restrict__ QKV,
    const unsigned short* __restrict__ Vt,
    unsigned short* __restrict__ Omat) {
  __shared__ unsigned short Ks[64 * 64];   // [kv][d], chunk-swizzled
  __shared__ unsigned short Vs[64 * 64];   // [d][kv], chunk-swizzled
  __shared__ unsigned short Ps[4][16 * PLD];
  int tid = threadIdx.x;
  int lane = tid & 63, wave = tid >> 6;
  int quad = lane >> 4, l16 = lane & 15;
  int z = blockIdx.x;
  int bh = z & 31;
  int qt = 31 - (z >> 5);          // heavy blocks dispatch first
  int b = bh >> 4, h = bh & 15;
  long rowbase = (long)b * SEQ;
  int hd0 = h * 64;
  unsigned short* pw = &Ps[wave][0];
  const float SCL = 0.18033688f;   // 0.125 * log2(e)
  const floatx4 fz = {0.f, 0.f, 0.f, 0.f};

  int r_in = lane >> 3;
  int cpos = lane & 7;

  bf16x8 ones;
  #pragma unroll
  for (int i = 0; i < 8; i++) ones[i] = (__bf16)1.0f;

  int q0w = qt * 64 + wave * 16;
  int qrow = q0w + quad * 4;
  int ntiles = qt + 1;

  bf16x8 qf0, qf1;
  {
    const unsigned short* qp_ =
        QKV + (rowbase + q0w + l16) * (long)QKV_LD + hd0 + quad * 8;
    qf0 = *(const bf16x8*)(qp_);
    qf1 = *(const bf16x8*)(qp_ + 32);
  }

  floatx4 ao[4], aol;
  #pragma unroll
  for (int t = 0; t < 4; t++) ao[t] = fz;
  aol = fz;
  float m_i[4];
  #pragma unroll
  for (int r = 0; r < 4; r++) m_i[r] = -3.0e38f;

  for (int it = 0; it < ntiles; it++) {
    int kv0 = it << 6;
    #pragma unroll
    for (int jj = 0; jj < 2; jj++) {
      int j = wave * 2 + jj;
      int r = j * 8 + r_in;
      int c = cpos ^ (r & 7);
      const unsigned short* gk =
          QKV + (rowbase + kv0 + r) * (long)QKV_LD + 1024 + hd0 + c * 8;
      async16(gk, Ks + j * 512);
      const unsigned short* gv =
          Vt + (long)(hd0 + r) * NROWS + rowbase + kv0 + c * 8;
      async16(gv, Vs + j * 512);
    }
    __syncthreads();

    floatx4 sacc[4];
    #pragma unroll
    for (int t = 0; t < 4; t++) {
      int row = t * 16 + l16;
      int sw = row & 7;
      bf16x8 kf0 = *(const bf16x8*)(Ks + row * 64 + (quad ^ sw) * 8);
      bf16x8 kf1 = *(const bf16x8*)(Ks + row * 64 + ((quad + 4) ^ sw) * 8);
      sacc[t] = __builtin_amdgcn_mfma_f32_16x16x32_bf16(qf0, kf0, fz, 0, 0, 0);
      sacc[t] = __builtin_amdgcn_mfma_f32_16x16x32_bf16(qf1, kf1, sacc[t], 0, 0, 0);
    }

    // causal mask on RAW scores (only the diagonal tile)
    if (it == ntiles - 1) {
      #pragma unroll
      for (int t = 0; t < 4; t++) {
        int kvc = kv0 + t * 16 + l16;
        #pragma unroll
        for (int r = 0; r < 4; r++)
          sacc[t][r] = (kvc > qrow + r) ? -1.0e30f : sacc[t][r];
      }
    }

    // max over raw scores (scale commutes with max: SCL > 0)
    float Mg = sacc[0][0];
    #pragma unroll
    for (int t = 0; t < 4; t++)
      #pragma unroll
      for (int r = 0; r < 4; r++) Mg = fmaxf(Mg, sacc[t][r]);
    Mg = fmaxf(Mg, ror16<1>(Mg));
    Mg = fmaxf(Mg, ror16<2>(Mg));
    Mg = fmaxf(Mg, ror16<4>(Mg));
    Mg = fmaxf(Mg, ror16<8>(Mg));
    float Mg_s = Mg * SCL;

    // defer-max: rescale only if the running max grew by > 8
    float m_min = fminf(fminf(m_i[0], m_i[1]), fminf(m_i[2], m_i[3]));
    if (Mg_s > m_min + 8.0f) {
      #pragma unroll
      for (int r = 0; r < 4; r++) {
        float mn = fmaxf(m_i[r], Mg_s);
        float alpha = __builtin_amdgcn_exp2f(m_i[r] - mn);
        m_i[r] = mn;
        #pragma unroll
        for (int t = 0; t < 4; t++) ao[t][r] *= alpha;
        aol[r] *= alpha;
      }
    }

    #pragma unroll
    for (int t = 0; t < 4; t++)
      #pragma unroll
      for (int r = 0; r < 4; r++) {
        float p = __builtin_amdgcn_exp2f(fmaf(sacc[t][r], SCL, -m_i[r]));
        pw[(quad * 4 + r) * PLD + t * 16 + l16] =
            (unsigned short)(__float_as_uint(p) >> 16);
      }

    __asm__ volatile("s_waitcnt lgkmcnt(0)" ::: "memory");
    bf16x8 pf0 = *(const bf16x8*)(pw + l16 * PLD + quad * 8);
    bf16x8 pf1 = *(const bf16x8*)(pw + l16 * PLD + 32 + quad * 8);

    #pragma unroll
    for (int t = 0; t < 4; t++) {
      int row = t * 16 + l16;
      int sw = row & 7;
      bf16x8 vf0 = *(const bf16x8*)(Vs + row * 64 + (quad ^ sw) * 8);
      bf16x8 vf1 = *(const bf16x8*)(Vs + row * 64 + ((quad + 4) ^ sw) * 8);
      ao[t] = __builtin_amdgcn_mfma_f32_16x16x32_bf16(pf0, vf0, ao[t], 0, 0, 0);
      ao[t] = __builtin_amdgcn_mfma_f32_16x16x32_bf16(pf1, vf1, ao[t], 0, 0, 0);
    }
    aol = __builtin_amdgcn_mfma_f32_16x16x32_bf16(pf0, ones, aol, 0, 0, 0);
    aol = __builtin_amdgcn_mfma_f32_16x16x32_bf16(pf1, ones, aol, 0, 0, 0);

    __syncthreads();
  }

  float inv[4];
  #pragma unroll
  for (int r = 0; r < 4; r++) inv[r] = 1.0f / aol[r];
  #pragma unroll
  for (int t = 0; t < 4; t++)
    #pragma unroll
    for (int r = 0; r < 4; r++)
      Omat[(rowbase + qrow + r) * (long)D_MODEL + hd0 + t * 16 + l16] =
          f2bf(ao[t][r] * inv[r]);
}

// -------- fused residual add (x + partial) + layernorm --------
__global__ __launch_bounds__(256) void k_add_ln(
    const float* __restrict__ A, const float* __restrict__ P,
    const float* __restrict__ g, const float* __restrict__ be,
    float* __restrict__ Y, unsigned short* __restrict__ Ybf) {
  __shared__ float sb[4], ssb[4];
  int tid = threadIdx.x;
  long base = (long)blockIdx.x * D_MODEL + tid * 4;
  float4 a  = *(const float4*)(A + base);
  float4 p0 = *(const float4*)(P + base);
  float v0 = a.x + p0.x;
  float v1 = a.y + p0.y;
  float v2 = a.z + p0.z;
  float v3 = a.w + p0.w;
  float s  = v0 + v1 + v2 + v3;
  float ss = v0 * v0 + v1 * v1 + v2 * v2 + v3 * v3;
  #pragma unroll
  for (int o = 32; o >= 1; o >>= 1) {
    s  += __shfl_xor(s, o, 64);
    ss += __shfl_xor(ss, o, 64);
  }
  int wave = tid >> 6;
  if ((tid & 63) == 0) { sb[wave] = s; ssb[wave] = ss; }
  __syncthreads();
  s  = sb[0] + sb[1] + sb[2] + sb[3];
  ss = ssb[0] + ssb[1] + ssb[2] + ssb[3];
  float mu  = s * (1.0f / 1024.0f);
  float var = ss * (1.0f / 1024.0f) - mu * mu;
  float rstd = rsqrtf(var + 1e-6f);
  float4 gv  = *(const float4*)(g + tid * 4);
  float4 bev = *(const float4*)(be + tid * 4);
  float o0 = (v0 - mu) * rstd * gv.x + bev.x;
  float o1 = (v1 - mu) * rstd * gv.y + bev.y;
  float o2 = (v2 - mu) * rstd * gv.z + bev.z;
  float o3 = (v3 - mu) * rstd * gv.w + bev.w;
  if (Y) *(float4*)(Y + base) = make_float4(o0, o1, o2, o3);
  if (Ybf) {
    ushort4 u;
    u.x = f2bf(o0); u.y = f2bf(o1); u.z = f2bf(o2); u.w = f2bf(o3);
    *(ushort4*)(Ybf + base) = u;
  }
}

extern "C" void kernel_launch(void* const* d_in, const int* in_sizes, int n_in,
                              void* d_out, int out_size, void* d_ws, size_t ws_size,
                              hipStream_t stream) {
  (void)in_sizes; (void)n_in; (void)out_size; (void)ws_size;
  const float* x   = (const float*)d_in[0];
  const float* Wq  = (const float*)d_in[1];
  const float* bq  = (const float*)d_in[2];
  const float* Wk  = (const float*)d_in[3];
  const float* bk  = (const float*)d_in[4];
  const float* Wv  = (const float*)d_in[5];
  const float* bv  = (const float*)d_in[6];
  const float* Wo  = (const float*)d_in[7];
  const float* bo  = (const float*)d_in[8];
  const float* g1  = (const float*)d_in[9];
  const float* b1  = (const float*)d_in[10];
  const float* Wup = (const float*)d_in[11];
  const float* bup = (const float*)d_in[12];
  const float* Wdn = (const float*)d_in[13];
  const float* bdn = (const float*)d_in[14];
  const float* g2  = (const float*)d_in[15];
  const float* b2  = (const float*)d_in[16];
  float* out = (float*)d_out;

  char* ws = (char*)d_ws;
  size_t off = 0;
  auto alloc = [&](size_t bytes) {
    char* p = ws + off;
    off = (off + bytes + 255) & ~(size_t)255;
    return p;
  };
  unsigned short* x_bf   = (unsigned short*)alloc((size_t)NROWS * D_MODEL * 2);
  unsigned short* WqkvT  = (unsigned short*)alloc((size_t)QKV_LD * D_MODEL * 2);
  unsigned short* WoT    = (unsigned short*)alloc((size_t)D_MODEL * D_MODEL * 2);
  unsigned short* WupT   = (unsigned short*)alloc((size_t)D_FFN * D_MODEL * 2);
  unsigned short* WdnT   = (unsigned short*)alloc((size_t)D_MODEL * D_FFN * 2);
  float*          bqkv   = (float*)alloc((size_t)QKV_LD * 4);
  unsigned short* qkv_bf = (unsigned short*)alloc((size_t)NROWS * QKV_LD * 2);
  unsigned short* Vt     = (unsigned short*)alloc((size_t)D_MODEL * NROWS * 2);
  unsigned short* mid_bf = (unsigned short*)alloc((size_t)NROWS * D_MODEL * 2);
  float*          x1f    = (float*)alloc((size_t)NROWS * D_MODEL * 4);
  unsigned short* x1bf   = (unsigned short*)alloc((size_t)NROWS * D_MODEL * 2);
  float*          part   = (float*)alloc((size_t)NROWS * D_MODEL * 4);
  unsigned short* h_bf   = (unsigned short*)alloc((size_t)NROWS * D_FFN * 2);

  k_f32_to_bf16<<<4096, 256, 0, stream>>>(x, x_bf, (long)NROWS * D_MODEL);
  k_transpose_sq<<<dim3(32, 32, 4), 256, 0, stream>>>(Wq, Wk, Wv, Wo, WqkvT, WoT);
  k_transpose_bf16<<<dim3(128, 32), 256, 0, stream>>>(Wup, WupT, D_MODEL, D_FFN);
  k_transpose_bf16<<<dim3(32, 128), 256, 0, stream>>>(Wdn, WdnT, D_FFN, D_MODEL);
  k_pack_bias<<<12, 256, 0, stream>>>(bq, bk, bv, bqkv);

  // QKV: M=4096, N=3072, K=1024 -> 768 blocks (2/CU)
  k_gemm128<<<dim3(32, 24), 256, 0, stream>>>(x_bf, WqkvT, bqkv, qkv_bf,
                                              NROWS, QKV_LD, D_MODEL, 0, 4, 2);
  k_transpose_v<<<dim3(64, 16), 256, 0, stream>>>(qkv_bf, Vt);

  // 1024 blocks: 32 q-tiles x 32 (b,h), heavy-first; whole grid co-resident
  k_attn<<<1024, 256, 0, stream>>>(qkv_bf, Vt, mid_bf);

  // Wo: M=4096, N=1024, K=1024 -> 256 blocks, f32 out
  k_gemm128<<<dim3(32, 8), 256, 0, stream>>>(mid_bf, WoT, bo, part,
                                             NROWS, D_MODEL, D_MODEL, 1, 4, 2);
  k_add_ln<<<4096, 256, 0, stream>>>(x, part, g1, b1, x1f, x1bf);

  // Up: M=4096, N=4096, K=1024 -> 1024 blocks (2/CU)
  k_gemm128<<<dim3(32, 32), 256, 0, stream>>>(x1bf, WupT, bup, h_bf,
                                              NROWS, D_FFN, D_MODEL, 2, 4, 2);
  // Down: M=4096, N=1024, K=4096 -> 256 blocks, f32 out
  k_gemm128<<<dim3(32, 8), 256, 0, stream>>>(h_bf, WdnT, bdn, part,
                                             NROWS, D_MODEL, D_FFN, 1, 4, 2);
  k_add_ln<<<4096, 256, 0, stream>>>(x1f, part, g2, b2, out, nullptr);
}

// Round 9
// 318.696 us; speedup vs baseline: 1.1111x; 1.0502x over previous
//
#include <hip/hip_runtime.h>

#define D_MODEL 1024
#define D_FFN   4096
#define SEQ     2048
#define NROWS   4096   // B*S
#define QKV_LD  3072

typedef __bf16 bf16x8 __attribute__((ext_vector_type(8)));
typedef float  floatx4 __attribute__((ext_vector_type(4)));

#define MFMA_BF16 __builtin_amdgcn_mfma_f32_16x16x32_bf16

__device__ __forceinline__ unsigned short f2bf(float f) {
  unsigned int u = __float_as_uint(f);
  u += 0x7FFFu + ((u >> 16) & 1u);   // RNE
  return (unsigned short)(u >> 16);
}

// DPP row_ror<N> within 16-lane rows (VALU-speed cross-lane; no LDS pipe)
template <int C>
__device__ __forceinline__ float ror16(float x) {
  return __int_as_float(
      __builtin_amdgcn_mov_dpp(__float_as_int(x), 0x120 | C, 0xf, 0xf, true));
}

// async global->LDS, 16B per lane. LDS dest = wave-uniform base + lane*16.
__device__ __forceinline__ void async16(const unsigned short* g, unsigned short* l) {
  __builtin_amdgcn_global_load_lds(
      (const __attribute__((address_space(1))) unsigned int*)g,
      (__attribute__((address_space(3))) unsigned int*)l, 16, 0, 0);
}

// ================= fused prep: all weight transposes + x convert + bias =================
// One launch replaces 5 serial kernels; independent zones run concurrently.
// zones (flat blockIdx.x):
//   [0,4096)      x f32->bf16 (4 elems/thread)
//   [4096,8192)   Wq/Wk/Wv/Wo 1024x1024 transpose->bf16 (z=(b-4096)>>10)
//   [8192,12288)  Wup (1024x4096) transpose -> WupT[4096][1024]
//   [12288,16384) Wdn (4096x1024) transpose -> WdnT[1024][4096]
//   [16384,16396) bias pack (3072 floats)
__global__ __launch_bounds__(256) void k_prep(
    const float* __restrict__ x,
    const float* __restrict__ Wq, const float* __restrict__ Wk,
    const float* __restrict__ Wv, const float* __restrict__ Wo,
    const float* __restrict__ Wup, const float* __restrict__ Wdn,
    const float* __restrict__ bq, const float* __restrict__ bk,
    const float* __restrict__ bv,
    unsigned short* __restrict__ x_bf, unsigned short* __restrict__ WqkvT,
    unsigned short* __restrict__ WoT, unsigned short* __restrict__ WupT,
    unsigned short* __restrict__ WdnT, float* __restrict__ bqkv) {
  __shared__ float tile[32][33];
  int b = blockIdx.x;
  if (b < 4096) {
    long i = ((long)b * 256 + threadIdx.x) * 4;
    float4 v = *(const float4*)(x + i);
    ushort4 o;
    o.x = f2bf(v.x); o.y = f2bf(v.y); o.z = f2bf(v.z); o.w = f2bf(v.w);
    *(ushort4*)(x_bf + i) = o;
    return;
  }
  if (b >= 16384) {
    int i = (b - 16384) * 256 + threadIdx.x;
    if (i < 3072) {
      float v = (i < 1024) ? bq[i] : (i < 2048) ? bk[i - 1024] : bv[i - 2048];
      bqkv[i] = v;
    }
    return;
  }
  // transpose zones: W[R][C] -> WT[C][R], 32x32 tile at (bx over C, by over R)
  const float* W; unsigned short* WT; int R, C, bx, by;
  if (b < 8192) {
    int z = (b - 4096) >> 10, idx = (b - 4096) & 1023;
    W = (z == 0) ? Wq : (z == 1) ? Wk : (z == 2) ? Wv : Wo;
    WT = (z < 3) ? (WqkvT + (size_t)z * D_MODEL * D_MODEL) : WoT;
    R = D_MODEL; C = D_MODEL; bx = idx & 31; by = idx >> 5;
  } else if (b < 12288) {
    int idx = b - 8192;
    W = Wup; WT = WupT; R = D_MODEL; C = D_FFN; bx = idx & 127; by = idx >> 7;
  } else {
    int idx = b - 12288;
    W = Wdn; WT = WdnT; R = D_FFN; C = D_MODEL; bx = idx & 31; by = idx >> 5;
  }
  int tx = threadIdx.x & 31, ty = threadIdx.x >> 5;
  long gx = (long)bx * 32, gy = (long)by * 32;
  #pragma unroll
  for (int j = 0; j < 4; j++)
    tile[ty + j * 8][tx] = W[(gy + ty + j * 8) * C + gx + tx];
  __syncthreads();
  #pragma unroll
  for (int j = 0; j < 4; j++)
    WT[(gx + ty + j * 8) * R + gy + tx] = f2bf(tile[tx][ty + j * 8]);
}

// ============ 128x128 8-wave bf16 MFMA GEMM, counted vmcnt, 2D XCD chunking ============
// C[M][N] = A[M][K] @ Bt[N][K]^T + bias. BK=64, double-buffered 64 KiB static LDS.
// 512 threads as 2M x 4N waves (64x32/wave, acc[4][2]): 2 waves/SIMD even at
// 1 block/CU (intra-SIMD latency hiding the 4-wave config lacked).
// Schedule: no intra-phase waitcnt pins -- reads grouped {ca0}{ca1}, MFMAs {h0}{h1};
// compiler emits counted lgkmcnt covering ca1 reads under h0 MFMAs.
// flags: bit0 f32out, bit1 relu, bit2 V-transpose (blocks with bn>=2048 write
// their tile transposed into VtOut[d][row] instead of C -- kills k_transpose_v).
__global__ __launch_bounds__(512, 2) void k_gemm128(
    const unsigned short* __restrict__ A,
    const unsigned short* __restrict__ Bt,
    const float* __restrict__ bias,
    void* __restrict__ Cp, unsigned short* __restrict__ VtOut,
    int M, int N, int K, int flags, int rx, int ry) {
  __shared__ unsigned short lds[2 * 16384];   // [2 buf][A 8192 | B 8192] u16 = 64 KiB
  int tid = threadIdx.x, lane = tid & 63, wave = tid >> 6;
  int quad = lane >> 4, l16 = lane & 15;
  int wm = wave >> 2, wn = wave & 3;          // 2M x 4N wave grid

  int nx = gridDim.x, ny = gridDim.y;
  int orig = blockIdx.y * nx + blockIdx.x;
  int xcd = orig & 7;                 // assumes round-robin dispatch->XCD (perf-only)
  int s = orig >> 3;                  // sequence within this XCD
  int mr = nx / rx, mc = ny / ry;     // tiles per rect
  int rr = xcd / ry, rc = xcd % ry;
  int im = s % mr, in_ = s / mr;      // im-fast: concurrent blocks share B-panels
  long bm = (long)(rr * mr + im) * 128;
  long bn = (long)(rc * mc + in_) * 128;

  int T = K / 64;

  const floatx4 fz = {0.f, 0.f, 0.f, 0.f};
  floatx4 acc[4][2];
  #pragma unroll
  for (int i = 0; i < 4; i++)
    #pragma unroll
    for (int j = 0; j < 2; j++) acc[i][j] = fz;

  int srow = tid >> 3;
  int sc = (tid & 7) ^ (srow & 7);
  const unsigned short* Ag = A + (bm + srow) * (long)K + sc * 8;
  const unsigned short* Bg = Bt + (bn + srow) * (long)K + sc * 8;

  auto stage = [&](int tt, int c) {
    unsigned short* An = lds + c * 16384;
    unsigned short* Bn = An + 8192;
    long ko = (long)tt * 64;
    async16(Ag + ko, An + wave * 512);
    async16(Ag + 64 * (long)K + ko, An + 4096 + wave * 512);
    async16(Bg + ko, Bn + wave * 512);
    async16(Bg + 64 * (long)K + ko, Bn + 4096 + wave * 512);
  };

  int aoff = (wm * 64 + l16) * 64;
  int boff = (wn * 32 + l16) * 64;
  int sw = l16 & 7;
  int ca0 = (quad ^ sw) * 8;          // k-chunks 0..3 (h=0)
  int ca1 = ((4 + quad) ^ sw) * 8;    // k-chunks 4..7 (h=1)

  stage(0, 0);
  for (int t = 0; t < T; t++) {
    int c = t & 1;
    const unsigned short* Ac = lds + c * 16384;
    const unsigned short* Bc = Ac + 8192;
    int tn = (t + 1 < T) ? t + 1 : T - 1;   // clamp keeps vmcnt count uniform
    stage(tn, c ^ 1);
    __asm__ volatile("s_waitcnt vmcnt(4)" ::: "memory");
    __builtin_amdgcn_s_barrier();

    bf16x8 af0[4], bf0[2], af1[4], bf1[2];
    #pragma unroll
    for (int m = 0; m < 4; m++) af0[m] = *(const bf16x8*)(Ac + aoff + m * 1024 + ca0);
    #pragma unroll
    for (int n = 0; n < 2; n++) bf0[n] = *(const bf16x8*)(Bc + boff + n * 1024 + ca0);
    #pragma unroll
    for (int m = 0; m < 4; m++) af1[m] = *(const bf16x8*)(Ac + aoff + m * 1024 + ca1);
    #pragma unroll
    for (int n = 0; n < 2; n++) bf1[n] = *(const bf16x8*)(Bc + boff + n * 1024 + ca1);
    #pragma unroll
    for (int m = 0; m < 4; m++)
      #pragma unroll
      for (int n = 0; n < 2; n++)
        acc[m][n] = MFMA_BF16(af0[m], bf0[n], acc[m][n], 0, 0, 0);
    #pragma unroll
    for (int m = 0; m < 4; m++)
      #pragma unroll
      for (int n = 0; n < 2; n++)
        acc[m][n] = MFMA_BF16(af1[m], bf1[n], acc[m][n], 0, 0, 0);
    __builtin_amdgcn_s_barrier();
  }

  bool f32out = (flags & 1) != 0;
  bool relu   = (flags & 2) != 0;
  bool vtr    = (flags & 4) != 0 && bn >= 2048;
  if (f32out) {
    float* outf = (float*)Cp;
    #pragma unroll
    for (int n = 0; n < 2; n++) {
      long col = bn + wn * 32 + n * 16 + l16;
      float bvv = bias[col];
      #pragma unroll
      for (int m = 0; m < 4; m++) {
        long row = bm + wm * 64 + m * 16 + quad * 4;
        #pragma unroll
        for (int r = 0; r < 4; r++) {
          float v = acc[m][n][r] + bvv;
          if (relu) v = fmaxf(v, 0.0f);
          outf[(row + r) * (long)N + col] = v;
        }
      }
    }
  } else if (vtr) {
    // V tile: write transposed to VtOut[d][row], d = col-2048.
    __asm__ volatile("s_waitcnt vmcnt(0)" ::: "memory");
    __syncthreads();
    // per-wave transposed tile: 32 cols x 64 rows, row stride 72 u16
    unsigned short* lwT = lds + wave * 2304;
    #pragma unroll
    for (int n = 0; n < 2; n++) {
      long col = bn + wn * 32 + n * 16 + l16;
      float bvv = bias[col];
      ushort4 u;
      #pragma unroll
      for (int m = 0; m < 4; m++) {
        u.x = f2bf(acc[m][0 + n][0] + bvv);   // r=0..3 consecutive rows
        u.y = f2bf(acc[m][n][1] + bvv);
        u.z = f2bf(acc[m][n][2] + bvv);
        u.w = f2bf(acc[m][n][3] + bvv);
        *(ushort4*)(lwT + (n * 16 + l16) * 72 + m * 16 + quad * 4) = u;
      }
    }
    __syncthreads();
    long d0 = bn - 2048 + wn * 32;
    long grow = bm + wm * 64;
    int rseg = (lane & 7) * 8;
    #pragma unroll
    for (int k = 0; k < 4; k++) {
      int cl = k * 8 + (lane >> 3);
      bf16x8 vv = *(const bf16x8*)(lwT + cl * 72 + rseg);
      *(bf16x8*)(VtOut + (d0 + cl) * (long)NROWS + grow + rseg) = vv;
    }
  } else {
    // drain in-flight dummy stage writes before reusing LDS, then barrier
    __asm__ volatile("s_waitcnt vmcnt(0)" ::: "memory");
    __syncthreads();
    unsigned short* outh = (unsigned short*)Cp;
    // per-wave private 64x32 u16 tile, row stride 40 u16
    unsigned short* lw = lds + wave * 2560;
    #pragma unroll
    for (int n = 0; n < 2; n++) {
      long col = bn + wn * 32 + n * 16 + l16;
      float bvv = bias[col];
      #pragma unroll
      for (int m = 0; m < 4; m++) {
        #pragma unroll
        for (int r = 0; r < 4; r++) {
          float v = acc[m][n][r] + bvv;
          if (relu) v = fmaxf(v, 0.0f);
          lw[(m * 16 + quad * 4 + r) * 40 + n * 16 + l16] = f2bf(v);
        }
      }
    }
    int rrb = lane >> 2;
    int c8 = (lane & 3) * 8;
    long grow = bm + wm * 64;
    long gcol = bn + wn * 32 + c8;
    #pragma unroll
    for (int k = 0; k < 4; k++) {
      int rw = rrb + k * 16;
      bf16x8 vv = *(const bf16x8*)(lw + rw * 40 + c8);
      *(bf16x8*)(outh + (grow + rw) * (long)N + gcol) = vv;
    }
  }
}

// ---------------- flash attention (causal), LDS-staged K/V ----------------
// One q-tile (64 rows) per block; 1024 blocks, heavy-first (qt descending).
#define PLD 72
__global__ __launch_bounds__(256) void k_attn(
    const unsigned short* __restrict__ QKV,
    const unsigned short* __restrict__ Vt,
    unsigned short* __restrict__ Omat) {
  __shared__ unsigned short Ks[64 * 64];   // [kv][d], chunk-swizzled
  __shared__ unsigned short Vs[64 * 64];   // [d][kv], chunk-swizzled
  __shared__ unsigned short Ps[4][16 * PLD];
  int tid = threadIdx.x;
  int lane = tid & 63, wave = tid >> 6;
  int quad = lane >> 4, l16 = lane & 15;
  int z = blockIdx.x;
  int bh = z & 31;
  int qt = 31 - (z >> 5);          // heavy blocks dispatch first
  int b = bh >> 4, h = bh & 15;
  long rowbase = (long)b * SEQ;
  int hd0 = h * 64;
  unsigned short* pw = &Ps[wave][0];
  const float SCL = 0.18033688f;   // 0.125 * log2(e)
  const floatx4 fz = {0.f, 0.f, 0.f, 0.f};

  int r_in = lane >> 3;
  int cpos = lane & 7;

  bf16x8 ones;
  #pragma unroll
  for (int i = 0; i < 8; i++) ones[i] = (__bf16)1.0f;

  int q0w = qt * 64 + wave * 16;
  int qrow = q0w + quad * 4;
  int ntiles = qt + 1;

  bf16x8 qf0, qf1;
  {
    const unsigned short* qp_ =
        QKV + (rowbase + q0w + l16) * (long)QKV_LD + hd0 + quad * 8;
    qf0 = *(const bf16x8*)(qp_);
    qf1 = *(const bf16x8*)(qp_ + 32);
  }

  floatx4 ao[4], aol;
  #pragma unroll
  for (int t = 0; t < 4; t++) ao[t] = fz;
  aol = fz;
  float m_i[4];
  #pragma unroll
  for (int r = 0; r < 4; r++) m_i[r] = -3.0e38f;

  for (int it = 0; it < ntiles; it++) {
    int kv0 = it << 6;
    #pragma unroll
    for (int jj = 0; jj < 2; jj++) {
      int j = wave * 2 + jj;
      int r = j * 8 + r_in;
      int c = cpos ^ (r & 7);
      const unsigned short* gk =
          QKV + (rowbase + kv0 + r) * (long)QKV_LD + 1024 + hd0 + c * 8;
      async16(gk, Ks + j * 512);
      const unsigned short* gv =
          Vt + (long)(hd0 + r) * NROWS + rowbase + kv0 + c * 8;
      async16(gv, Vs + j * 512);
    }
    __syncthreads();

    floatx4 sacc[4];
    #pragma unroll
    for (int t = 0; t < 4; t++) {
      int row = t * 16 + l16;
      int sw = row & 7;
      bf16x8 kf0 = *(const bf16x8*)(Ks + row * 64 + (quad ^ sw) * 8);
      bf16x8 kf1 = *(const bf16x8*)(Ks + row * 64 + ((quad + 4) ^ sw) * 8);
      sacc[t] = __builtin_amdgcn_mfma_f32_16x16x32_bf16(qf0, kf0, fz, 0, 0, 0);
      sacc[t] = __builtin_amdgcn_mfma_f32_16x16x32_bf16(qf1, kf1, sacc[t], 0, 0, 0);
    }

    // causal mask on RAW scores (only the diagonal tile)
    if (it == ntiles - 1) {
      #pragma unroll
      for (int t = 0; t < 4; t++) {
        int kvc = kv0 + t * 16 + l16;
        #pragma unroll
        for (int r = 0; r < 4; r++)
          sacc[t][r] = (kvc > qrow + r) ? -1.0e30f : sacc[t][r];
      }
    }

    // max over raw scores (scale commutes with max: SCL > 0)
    float Mg = sacc[0][0];
    #pragma unroll
    for (int t = 0; t < 4; t++)
      #pragma unroll
      for (int r = 0; r < 4; r++) Mg = fmaxf(Mg, sacc[t][r]);
    Mg = fmaxf(Mg, ror16<1>(Mg));
    Mg = fmaxf(Mg, ror16<2>(Mg));
    Mg = fmaxf(Mg, ror16<4>(Mg));
    Mg = fmaxf(Mg, ror16<8>(Mg));
    float Mg_s = Mg * SCL;

    // defer-max: rescale only if the running max grew by > 8
    float m_min = fminf(fminf(m_i[0], m_i[1]), fminf(m_i[2], m_i[3]));
    if (Mg_s > m_min + 8.0f) {
      #pragma unroll
      for (int r = 0; r < 4; r++) {
        float mn = fmaxf(m_i[r], Mg_s);
        float alpha = __builtin_amdgcn_exp2f(m_i[r] - mn);
        m_i[r] = mn;
        #pragma unroll
        for (int t = 0; t < 4; t++) ao[t][r] *= alpha;
        aol[r] *= alpha;
      }
    }

    #pragma unroll
    for (int t = 0; t < 4; t++)
      #pragma unroll
      for (int r = 0; r < 4; r++) {
        float p = __builtin_amdgcn_exp2f(fmaf(sacc[t][r], SCL, -m_i[r]));
        pw[(quad * 4 + r) * PLD + t * 16 + l16] =
            (unsigned short)(__float_as_uint(p) >> 16);
      }

    __asm__ volatile("s_waitcnt lgkmcnt(0)" ::: "memory");
    bf16x8 pf0 = *(const bf16x8*)(pw + l16 * PLD + quad * 8);
    bf16x8 pf1 = *(const bf16x8*)(pw + l16 * PLD + 32 + quad * 8);

    #pragma unroll
    for (int t = 0; t < 4; t++) {
      int row = t * 16 + l16;
      int sw = row & 7;
      bf16x8 vf0 = *(const bf16x8*)(Vs + row * 64 + (quad ^ sw) * 8);
      bf16x8 vf1 = *(const bf16x8*)(Vs + row * 64 + ((quad + 4) ^ sw) * 8);
      ao[t] = __builtin_amdgcn_mfma_f32_16x16x32_bf16(pf0, vf0, ao[t], 0, 0, 0);
      ao[t] = __builtin_amdgcn_mfma_f32_16x16x32_bf16(pf1, vf1, ao[t], 0, 0, 0);
    }
    aol = __builtin_amdgcn_mfma_f32_16x16x32_bf16(pf0, ones, aol, 0, 0, 0);
    aol = __builtin_amdgcn_mfma_f32_16x16x32_bf16(pf1, ones, aol, 0, 0, 0);

    __syncthreads();
  }

  float inv[4];
  #pragma unroll
  for (int r = 0; r < 4; r++) inv[r] = 1.0f / aol[r];
  #pragma unroll
  for (int t = 0; t < 4; t++)
    #pragma unroll
    for (int r = 0; r < 4; r++)
      Omat[(rowbase + qrow + r) * (long)D_MODEL + hd0 + t * 16 + l16] =
          f2bf(ao[t][r] * inv[r]);
}

// -------- fused residual add (x + partial) + layernorm --------
__global__ __launch_bounds__(256) void k_add_ln(
    const float* __restrict__ A, const float* __restrict__ P,
    const float* __restrict__ g, const float* __restrict__ be,
    float* __restrict__ Y, unsigned short* __restrict__ Ybf) {
  __shared__ float sb[4], ssb[4];
  int tid = threadIdx.x;
  long base = (long)blockIdx.x * D_MODEL + tid * 4;
  float4 a  = *(const float4*)(A + base);
  float4 p0 = *(const float4*)(P + base);
  float v0 = a.x + p0.x;
  float v1 = a.y + p0.y;
  float v2 = a.z + p0.z;
  float v3 = a.w + p0.w;
  float s  = v0 + v1 + v2 + v3;
  float ss = v0 * v0 + v1 * v1 + v2 * v2 + v3 * v3;
  #pragma unroll
  for (int o = 32; o >= 1; o >>= 1) {
    s  += __shfl_xor(s, o, 64);
    ss += __shfl_xor(ss, o, 64);
  }
  int wave = tid >> 6;
  if ((tid & 63) == 0) { sb[wave] = s; ssb[wave] = ss; }
  __syncthreads();
  s  = sb[0] + sb[1] + sb[2] + sb[3];
  ss = ssb[0] + ssb[1] + ssb[2] + ssb[3];
  float mu  = s * (1.0f / 1024.0f);
  float var = ss * (1.0f / 1024.0f) - mu * mu;
  float rstd = rsqrtf(var + 1e-6f);
  float4 gv  = *(const float4*)(g + tid * 4);
  float4 bev = *(const float4*)(be + tid * 4);
  float o0 = (v0 - mu) * rstd * gv.x + bev.x;
  float o1 = (v1 - mu) * rstd * gv.y + bev.y;
  float o2 = (v2 - mu) * rstd * gv.z + bev.z;
  float o3 = (v3 - mu) * rstd * gv.w + bev.w;
  if (Y) *(float4*)(Y + base) = make_float4(o0, o1, o2, o3);
  if (Ybf) {
    ushort4 u;
    u.x = f2bf(o0); u.y = f2bf(o1); u.z = f2bf(o2); u.w = f2bf(o3);
    *(ushort4*)(Ybf + base) = u;
  }
}

extern "C" void kernel_launch(void* const* d_in, const int* in_sizes, int n_in,
                              void* d_out, int out_size, void* d_ws, size_t ws_size,
                              hipStream_t stream) {
  (void)in_sizes; (void)n_in; (void)out_size; (void)ws_size;
  const float* x   = (const float*)d_in[0];
  const float* Wq  = (const float*)d_in[1];
  const float* bq  = (const float*)d_in[2];
  const float* Wk  = (const float*)d_in[3];
  const float* bk  = (const float*)d_in[4];
  const float* Wv  = (const float*)d_in[5];
  const float* bv  = (const float*)d_in[6];
  const float* Wo  = (const float*)d_in[7];
  const float* bo  = (const float*)d_in[8];
  const float* g1  = (const float*)d_in[9];
  const float* b1  = (const float*)d_in[10];
  const float* Wup = (const float*)d_in[11];
  const float* bup = (const float*)d_in[12];
  const float* Wdn = (const float*)d_in[13];
  const float* bdn = (const float*)d_in[14];
  const float* g2  = (const float*)d_in[15];
  const float* b2  = (const float*)d_in[16];
  float* out = (float*)d_out;

  char* ws = (char*)d_ws;
  size_t off = 0;
  auto alloc = [&](size_t bytes) {
    char* p = ws + off;
    off = (off + bytes + 255) & ~(size_t)255;
    return p;
  };
  unsigned short* x_bf   = (unsigned short*)alloc((size_t)NROWS * D_MODEL * 2);
  unsigned short* WqkvT  = (unsigned short*)alloc((size_t)QKV_LD * D_MODEL * 2);
  unsigned short* WoT    = (unsigned short*)alloc((size_t)D_MODEL * D_MODEL * 2);
  unsigned short* WupT   = (unsigned short*)alloc((size_t)D_FFN * D_MODEL * 2);
  unsigned short* WdnT   = (unsigned short*)alloc((size_t)D_MODEL * D_FFN * 2);
  float*          bqkv   = (float*)alloc((size_t)QKV_LD * 4);
  unsigned short* qkv_bf = (unsigned short*)alloc((size_t)NROWS * QKV_LD * 2);
  unsigned short* Vt     = (unsigned short*)alloc((size_t)D_MODEL * NROWS * 2);
  unsigned short* mid_bf = (unsigned short*)alloc((size_t)NROWS * D_MODEL * 2);
  float*          x1f    = (float*)alloc((size_t)NROWS * D_MODEL * 4);
  unsigned short* x1bf   = (unsigned short*)alloc((size_t)NROWS * D_MODEL * 2);
  float*          part   = (float*)alloc((size_t)NROWS * D_MODEL * 4);
  unsigned short* h_bf   = (unsigned short*)alloc((size_t)NROWS * D_FFN * 2);

  // one fused prep launch (x convert + 6 weight transposes + bias pack)
  k_prep<<<16396, 256, 0, stream>>>(x, Wq, Wk, Wv, Wo, Wup, Wdn, bq, bk, bv,
                                    x_bf, WqkvT, WoT, WupT, WdnT, bqkv);

  // QKV: M=4096, N=3072, K=1024 -> 768 blocks; V tiles (bn>=2048) write Vt directly
  k_gemm128<<<dim3(32, 24), 512, 0, stream>>>(x_bf, WqkvT, bqkv, qkv_bf, Vt,
                                              NROWS, QKV_LD, D_MODEL, 4, 4, 2);

  // 1024 blocks: 32 q-tiles x 32 (b,h), heavy-first; whole grid co-resident
  k_attn<<<1024, 256, 0, stream>>>(qkv_bf, Vt, mid_bf);

  // Wo: M=4096, N=1024, K=1024 -> 256 blocks, f32 out
  k_gemm128<<<dim3(32, 8), 512, 0, stream>>>(mid_bf, WoT, bo, part, nullptr,
                                             NROWS, D_MODEL, D_MODEL, 1, 4, 2);
  k_add_ln<<<4096, 256, 0, stream>>>(x, part, g1, b1, x1f, x1bf);

  // Up: M=4096, N=4096, K=1024 -> 1024 blocks (2/CU)
  k_gemm128<<<dim3(32, 32), 512, 0, stream>>>(x1bf, WupT, bup, h_bf, nullptr,
                                              NROWS, D_FFN, D_MODEL, 2, 4, 2);
  // Down: M=4096, N=1024, K=4096 -> 256 blocks, f32 out
  k_gemm128<<<dim3(32, 8), 512, 0, stream>>>(h_bf, WdnT, bdn, part, nullptr,
                                             NROWS, D_MODEL, D_FFN, 1, 4, 2);
  k_add_ln<<<4096, 256, 0, stream>>>(x1f, part, g2, b2, out, nullptr);
}